// Round 1
// baseline (637.606 us; speedup 1.0000x reference)
//
#include <hip/hip_runtime.h>
#include <math.h>

// Problem constants (fixed by the reference)
constexpr int kB    = 4;
constexpr int kN    = 3136;    // tokens per batch
constexpr int kN0   = 12544;   // points per batch
constexpr int kH    = 112, kW = 112;
constexpr int kHW   = kH * kW;          // 12544
constexpr int kCIN  = 128;
constexpr int kCHID = 512;
constexpr int kCOUT = 128;
constexpr int kROWS = kB * kN;          // 12544 token rows total
constexpr int kPTS  = kB * kN0;         // 50176 points total
constexpr int kBHW  = kB * kHW;         // 50176 cells total
constexpr float kEPS  = 1e-6f;
constexpr float kBEPS = 1e-5f;

__device__ __forceinline__ float gelu_f(float x) {
    return 0.5f * x * (1.0f + erff(x * 0.70710678118654752440f));
}

// ---------------------------------------------------------------------------
// GEMM: C[M,N] = A[M,K] * W[N,K]^T + bias[N]   (both weights are [N,K] row-major)
// 64x64 tile, BK=16, 256 threads, 4x4 micro-tile.
// ---------------------------------------------------------------------------
__global__ __launch_bounds__(256) void gemm_nt_bias(
    const float* __restrict__ A, const float* __restrict__ Wm,
    const float* __restrict__ bias, float* __restrict__ C,
    int M, int N, int K)
{
    __shared__ float As[16][64];
    __shared__ float Ws[16][64];
    const int bm = blockIdx.x * 64, bn = blockIdx.y * 64;
    const int tid = threadIdx.x;
    const int tx = tid & 15, ty = tid >> 4;
    const int lr = tid >> 2;          // 0..63 row within tile
    const int lk = (tid & 3) << 2;    // 0,4,8,12 k within tile
    float acc[4][4] = {};
    for (int k0 = 0; k0 < K; k0 += 16) {
        const float4 a4 = *(const float4*)(A  + (size_t)(bm + lr) * K + (k0 + lk));
        const float4 w4 = *(const float4*)(Wm + (size_t)(bn + lr) * K + (k0 + lk));
        __syncthreads();
        As[lk + 0][lr] = a4.x; As[lk + 1][lr] = a4.y; As[lk + 2][lr] = a4.z; As[lk + 3][lr] = a4.w;
        Ws[lk + 0][lr] = w4.x; Ws[lk + 1][lr] = w4.y; Ws[lk + 2][lr] = w4.z; Ws[lk + 3][lr] = w4.w;
        __syncthreads();
#pragma unroll
        for (int kk = 0; kk < 16; ++kk) {
            const float4 av = *(const float4*)&As[kk][ty * 4];
            const float4 wv = *(const float4*)&Ws[kk][tx * 4];
            const float a_[4] = {av.x, av.y, av.z, av.w};
            const float w_[4] = {wv.x, wv.y, wv.z, wv.w};
#pragma unroll
            for (int i = 0; i < 4; ++i)
#pragma unroll
                for (int j = 0; j < 4; ++j)
                    acc[i][j] = fmaf(a_[i], w_[j], acc[i][j]);
        }
    }
    const float4 bv = *(const float4*)(bias + bn + tx * 4);
#pragma unroll
    for (int i = 0; i < 4; ++i) {
        const size_t m = (size_t)(bm + ty * 4 + i);
        float4 o;
        o.x = acc[i][0] + bv.x; o.y = acc[i][1] + bv.y;
        o.z = acc[i][2] + bv.z; o.w = acc[i][3] + bv.w;
        *(float4*)(C + m * N + bn + tx * 4) = o;
    }
}

// ---------------------------------------------------------------------------
// Grid index from loc_orig (matches jnp: clip, *0.5+0.5, round-half-even, clip)
// ---------------------------------------------------------------------------
__global__ void grid_idx_k(const float* __restrict__ loc, int* __restrict__ idx_hw)
{
    const int p = blockIdx.x * 256 + threadIdx.x;
    if (p >= kPTS) return;
    float lx = loc[(size_t)p * 2 + 0];
    float ly = loc[(size_t)p * 2 + 1];
    lx = fminf(fmaxf(lx, -1.f), 1.f) * 0.5f + 0.5f;
    ly = fminf(fmaxf(ly, -1.f), 1.f) * 0.5f + 0.5f;
    int gx = (int)rintf(lx * (float)(kW - 1)); gx = min(max(gx, 0), kW - 1);
    int gy = (int)rintf(ly * (float)(kH - 1)); gy = min(max(gy, 0), kH - 1);
    idx_hw[p] = gy * kW + gx;
}

// ---------------------------------------------------------------------------
// Column stats over [rows, 512]: per-channel sum / sumsq (partial -> atomic)
// ---------------------------------------------------------------------------
__global__ __launch_bounds__(512) void colstats512_k(
    const float* __restrict__ X, float* __restrict__ gsum, float* __restrict__ gsq,
    int rows_per_blk)
{
    const int c = threadIdx.x;
    const int r0 = blockIdx.x * rows_per_blk;
    float s = 0.f, q = 0.f;
    for (int r = 0; r < rows_per_blk; ++r) {
        const float v = X[(size_t)(r0 + r) * kCHID + c];
        s += v; q += v * v;
    }
    atomicAdd(&gsum[c], s);
    atomicAdd(&gsq[c], q);
}

__global__ __launch_bounds__(256) void colstats128_k(
    const float* __restrict__ X, float* __restrict__ gsum, float* __restrict__ gsq,
    int rows_per_blk)
{
    const int c = threadIdx.x & 127;
    const int rr = threadIdx.x >> 7; // 0,1
    const int r0 = blockIdx.x * rows_per_blk;
    float s = 0.f, q = 0.f;
    for (int r = rr; r < rows_per_blk; r += 2) {
        const float v = X[(size_t)(r0 + r) * kCOUT + c];
        s += v; q += v * v;
    }
    atomicAdd(&gsum[c], s);
    atomicAdd(&gsq[c], q);
}

// scale/shift from stats: y = x*scale + shift == (x-mean)*g/sqrt(var+eps)+b
__global__ void bn_coef_k(const float* __restrict__ gsum, const float* __restrict__ gsq,
                          const float* __restrict__ g, const float* __restrict__ bb,
                          float* __restrict__ scale, float* __restrict__ shift,
                          int C, float invn)
{
    const int c = blockIdx.x * blockDim.x + threadIdx.x;
    if (c >= C) return;
    const float m = gsum[c] * invn;
    const float v = fmaxf(gsq[c] * invn - m * m, 0.f);
    const float sc = g[c] * rsqrtf(v + kBEPS);
    scale[c] = sc;
    shift[c] = bb[c] - m * sc;
}

// y = gelu(x*scale[c] + shift[c]), vectorized float4, channel-fastest layout
__global__ __launch_bounds__(256) void bn_act_k(
    const float* __restrict__ in, float* __restrict__ out,
    const float* __restrict__ scale, const float* __restrict__ shift,
    size_t n4, int c4div)
{
    const size_t stride = (size_t)gridDim.x * blockDim.x;
    for (size_t i = (size_t)blockIdx.x * blockDim.x + threadIdx.x; i < n4; i += stride) {
        const int c0 = (int)(i % (size_t)c4div) * 4;
        float4 v = ((const float4*)in)[i];
        const float4 sc = *(const float4*)(scale + c0);
        const float4 sh = *(const float4*)(shift + c0);
        v.x = gelu_f(fmaf(v.x, sc.x, sh.x));
        v.y = gelu_f(fmaf(v.y, sc.y, sh.y));
        v.z = gelu_f(fmaf(v.z, sc.z, sh.z));
        v.w = gelu_f(fmaf(v.w, sc.w, sh.w));
        ((float4*)out)[i] = v;
    }
}

// ---------------------------------------------------------------------------
// token2map scatter: one block per point; adds the token row into its cell row
// ---------------------------------------------------------------------------
__global__ __launch_bounds__(256) void scatter_map_k(
    const float* __restrict__ hpost, const int* __restrict__ idx_agg,
    const int* __restrict__ idx_hw, float* __restrict__ smap, float* __restrict__ cnt)
{
    const int p = blockIdx.x;
    const int b = p / kN0;
    const int ia = idx_agg[p];
    const int ih = idx_hw[p];
    const float2 v = ((const float2*)(hpost + ((size_t)b * kN + ia) * kCHID))[threadIdx.x];
    float* dst = smap + ((size_t)b * kHW + ih) * kCHID + threadIdx.x * 2;
    atomicAdd(dst + 0, v.x);
    atomicAdd(dst + 1, v.y);
    if (threadIdx.x == 0) atomicAdd(cnt + b * kHW + ih, 1.0f);
}

// rcnt = 1/(cnt+eps); empty cells -> 0 (lets conv skip loads & writes there)
__global__ void recip_k(const float* __restrict__ in, float* __restrict__ out,
                        int n, int zero_empty)
{
    const int i = blockIdx.x * 256 + threadIdx.x;
    if (i >= n) return;
    const float c = in[i];
    out[i] = (zero_empty && c == 0.f) ? 0.f : 1.f / (c + kEPS);
}

// ---------------------------------------------------------------------------
// Depthwise 3x3 conv, NHWC ([B,HW,512]); input normalized on the fly by rcnt.
// Skips empty output cells (never read) and empty neighbor loads (value 0).
// ---------------------------------------------------------------------------
__global__ __launch_bounds__(256) void dwconv_k(
    const float* __restrict__ smap, const float* __restrict__ rcnt,
    const float* __restrict__ wdw, const float* __restrict__ bdw,
    float* __restrict__ outm)
{
    const size_t i = (size_t)blockIdx.x * 256 + threadIdx.x;   // over B*HW*128
    const int c4 = (int)(i & 127);
    const int cb = (int)(i >> 7);         // 0..B*HW-1
    const int cell = cb % kHW;
    const int b = cb / kHW;
    const size_t mb = (size_t)b * kHW;
    if (rcnt[mb + cell] == 0.f) return;   // wave-uniform (64 lanes share a cell)
    const int y = cell / kW, x = cell % kW;
    const int c0 = c4 * 4;
    const float4 bv = *(const float4*)(bdw + c0);
    float a0 = bv.x, a1 = bv.y, a2 = bv.z, a3 = bv.w;
#pragma unroll
    for (int dy = 0; dy < 3; ++dy) {
        const int yy = y + dy - 1;
        if ((unsigned)yy >= (unsigned)kH) continue;
#pragma unroll
        for (int dx = 0; dx < 3; ++dx) {
            const int xx = x + dx - 1;
            if ((unsigned)xx >= (unsigned)kW) continue;
            const int nc = yy * kW + xx;
            const float r = rcnt[mb + nc];
            if (r == 0.f) continue;
            const float4 v = *(const float4*)(smap + (mb + nc) * kCHID + c0);
            const int wo = dy * 3 + dx;
            a0 = fmaf(wdw[(c0 + 0) * 9 + wo] * r, v.x, a0);
            a1 = fmaf(wdw[(c0 + 1) * 9 + wo] * r, v.y, a1);
            a2 = fmaf(wdw[(c0 + 2) * 9 + wo] * r, v.z, a2);
            a3 = fmaf(wdw[(c0 + 3) * 9 + wo] * r, v.w, a3);
        }
    }
    *(float4*)(outm + (mb + cell) * kCHID + c0) = make_float4(a0, a1, a2, a3);
}

// ---------------------------------------------------------------------------
// map2token scatter: one block per point; num[token] += w * conv_out[cell]
// ---------------------------------------------------------------------------
__global__ __launch_bounds__(256) void scatter_tok_k(
    const float* __restrict__ convo, const int* __restrict__ idx_agg,
    const int* __restrict__ idx_hw, const float* __restrict__ aw,
    float* __restrict__ num, float* __restrict__ den)
{
    const int p = blockIdx.x;
    const int b = p / kN0;
    const int ia = idx_agg[p];
    const int ih = idx_hw[p];
    const float w = aw[p];
    const float2 v = ((const float2*)(convo + ((size_t)b * kHW + ih) * kCHID))[threadIdx.x];
    float* dst = num + ((size_t)b * kN + ia) * kCHID + threadIdx.x * 2;
    atomicAdd(dst + 0, w * v.x);
    atomicAdd(dst + 1, w * v.y);
    if (threadIdx.x == 0) atomicAdd(den + b * kN + ia, w);
}

// h2 = h*dws[c] + num*rden[row]; write in place into num; fused BN2 stats
__global__ __launch_bounds__(512) void h2_stats_k(
    const float* __restrict__ hpost, float* __restrict__ num,
    const float* __restrict__ rden, const float* __restrict__ dws,
    float* __restrict__ gsum, float* __restrict__ gsq, int rows_per_blk)
{
    const int c = threadIdx.x;
    const float d = dws[c];
    const int r0 = blockIdx.x * rows_per_blk;
    float s = 0.f, q = 0.f;
    for (int r = 0; r < rows_per_blk; ++r) {
        const int row = r0 + r;
        const size_t i = (size_t)row * kCHID + c;
        const float v = fmaf(hpost[i], d, num[i] * rden[row]);
        num[i] = v;
        s += v; q += v * v;
    }
    atomicAdd(&gsum[c], s);
    atomicAdd(&gsq[c], q);
}

// ---------------------------------------------------------------------------
extern "C" void kernel_launch(void* const* d_in, const int* in_sizes, int n_in,
                              void* d_out, int out_size, void* d_ws, size_t ws_size,
                              hipStream_t stream)
{
    (void)in_sizes; (void)n_in; (void)out_size; (void)ws_size;
    const float* x    = (const float*)d_in[0];
    const float* loc  = (const float*)d_in[1];
    const int*   iagg = (const int*)  d_in[2];
    const float* aw   = (const float*)d_in[3];
    const float* fc1w = (const float*)d_in[4];
    const float* fc1b = (const float*)d_in[5];
    const float* g1   = (const float*)d_in[6];
    const float* b1   = (const float*)d_in[7];
    const float* dww  = (const float*)d_in[8];
    const float* dwb  = (const float*)d_in[9];
    const float* dwsw = (const float*)d_in[10];
    const float* g2   = (const float*)d_in[11];
    const float* b2   = (const float*)d_in[12];
    const float* fc2w = (const float*)d_in[13];
    const float* fc2b = (const float*)d_in[14];
    const float* g3   = (const float*)d_in[15];
    const float* b3   = (const float*)d_in[16];
    float* outp = (float*)d_out;

    float* ws = (float*)d_ws;
    // --- zeroed region (single memset) ---
    float* gsum1 = ws + 0;            // 512
    float* gsq1  = ws + 512;          // 512
    float* gsum2 = ws + 1024;         // 512
    float* gsq2  = ws + 1536;         // 512
    float* gsum3 = ws + 2048;         // 128
    float* gsq3  = ws + 2176;         // 128
    float* cnt   = ws + 2304;                 // 50176
    float* den   = cnt + (size_t)kBHW;        // 12544
    float* num   = den + (size_t)kROWS;       // 6,422,528  (tok accum -> h2 -> h3)
    float* smap  = num + (size_t)kROWS * kCHID; // 25,690,112
    const size_t zero_floats = 2304ull + kBHW + kROWS
                             + (size_t)kROWS * kCHID + (size_t)kBHW * kCHID; // 32,177,664
    // --- non-zeroed region ---
    float* scale1 = smap + (size_t)kBHW * kCHID;
    float* shift1 = scale1 + 512;
    float* scale2 = shift1 + 512;
    float* shift2 = scale2 + 512;
    float* scale3 = shift2 + 512;
    float* shift3 = scale3 + 128;
    float* rcnt   = shift3 + 128;             // 50176
    float* rden   = rcnt + (size_t)kBHW;      // 12544
    int*   ihw    = (int*)(rden + (size_t)kROWS);            // 50176 ints
    float* hbuf   = rden + (size_t)kROWS + (size_t)kPTS;     // 6,422,528 (h post-gelu)
    float* convo  = hbuf + (size_t)kROWS * kCHID;            // 25,690,112
    float* out3   = convo + (size_t)kBHW * kCHID;            // 1,605,632

    hipMemsetAsync(ws, 0, zero_floats * sizeof(float), stream);

    // fc1: h1[row, 512] = x[row,128] @ fc1_w[512,128]^T + b
    gemm_nt_bias<<<dim3(kROWS / 64, kCHID / 64), 256, 0, stream>>>(
        x, fc1w, fc1b, hbuf, kROWS, kCHID, kCIN);

    grid_idx_k<<<kPTS / 256, 256, 0, stream>>>(loc, ihw);

    colstats512_k<<<392, 512, 0, stream>>>(hbuf, gsum1, gsq1, 32);
    bn_coef_k<<<1, 512, 0, stream>>>(gsum1, gsq1, g1, b1, scale1, shift1, kCHID, 1.f / kROWS);
    bn_act_k<<<2048, 256, 0, stream>>>(hbuf, hbuf, scale1, shift1,
                                       (size_t)kROWS * kCHID / 4, kCHID / 4);

    scatter_map_k<<<kPTS, 256, 0, stream>>>(hbuf, iagg, ihw, smap, cnt);
    recip_k<<<kBHW / 256, 256, 0, stream>>>(cnt, rcnt, kBHW, 1);

    dwconv_k<<<(kB * kHW * (kCHID / 4)) / 256, 256, 0, stream>>>(smap, rcnt, dww, dwb, convo);

    scatter_tok_k<<<kPTS, 256, 0, stream>>>(convo, iagg, ihw, aw, num, den);
    recip_k<<<kROWS / 256, 256, 0, stream>>>(den, rden, kROWS, 0);

    h2_stats_k<<<392, 512, 0, stream>>>(hbuf, num, rden, dwsw, gsum2, gsq2, 32);
    bn_coef_k<<<1, 512, 0, stream>>>(gsum2, gsq2, g2, b2, scale2, shift2, kCHID, 1.f / kROWS);
    bn_act_k<<<2048, 256, 0, stream>>>(num, num, scale2, shift2,
                                       (size_t)kROWS * kCHID / 4, kCHID / 4);

    // fc2: out3[row,128] = h3[row,512] @ fc2_w[128,512]^T + b
    gemm_nt_bias<<<dim3(kROWS / 64, kCOUT / 64), 256, 0, stream>>>(
        num, fc2w, fc2b, out3, kROWS, kCOUT, kCHID);

    colstats128_k<<<392, 256, 0, stream>>>(out3, gsum3, gsq3, 32);
    bn_coef_k<<<1, 128, 0, stream>>>(gsum3, gsq3, g3, b3, scale3, shift3, kCOUT, 1.f / kROWS);
    bn_act_k<<<2048, 256, 0, stream>>>(out3, outp, scale3, shift3,
                                       (size_t)kROWS * kCOUT / 4, kCOUT / 4);
}

// Round 2
// 361.530 us; speedup vs baseline: 1.7636x; 1.7636x over previous
//
#include <hip/hip_runtime.h>
#include <math.h>

// Problem constants (fixed by the reference)
constexpr int kB    = 4;
constexpr int kN    = 3136;    // tokens per batch
constexpr int kN0   = 12544;   // points per batch
constexpr int kH    = 112, kW = 112;
constexpr int kHW   = kH * kW;          // 12544
constexpr int kCIN  = 128;
constexpr int kCHID = 512;
constexpr int kCOUT = 128;
constexpr int kROWS = kB * kN;          // 12544 token rows total
constexpr int kPTS  = kB * kN0;         // 50176 points total
constexpr int kBHW  = kB * kHW;         // 50176 cells total
constexpr float kEPS  = 1e-6f;
constexpr float kBEPS = 1e-5f;

__device__ __forceinline__ float gelu_f(float x) {
    return 0.5f * x * (1.0f + erff(x * 0.70710678118654752440f));
}

// ---------------------------------------------------------------------------
// GEMM: C[M,N] = A[M,K] * W[N,K]^T + bias[N]
// ---------------------------------------------------------------------------
__global__ __launch_bounds__(256) void gemm_nt_bias(
    const float* __restrict__ A, const float* __restrict__ Wm,
    const float* __restrict__ bias, float* __restrict__ C,
    int M, int N, int K)
{
    __shared__ float As[16][64];
    __shared__ float Ws[16][64];
    const int bm = blockIdx.x * 64, bn = blockIdx.y * 64;
    const int tid = threadIdx.x;
    const int tx = tid & 15, ty = tid >> 4;
    const int lr = tid >> 2;
    const int lk = (tid & 3) << 2;
    float acc[4][4] = {};
    for (int k0 = 0; k0 < K; k0 += 16) {
        const float4 a4 = *(const float4*)(A  + (size_t)(bm + lr) * K + (k0 + lk));
        const float4 w4 = *(const float4*)(Wm + (size_t)(bn + lr) * K + (k0 + lk));
        __syncthreads();
        As[lk + 0][lr] = a4.x; As[lk + 1][lr] = a4.y; As[lk + 2][lr] = a4.z; As[lk + 3][lr] = a4.w;
        Ws[lk + 0][lr] = w4.x; Ws[lk + 1][lr] = w4.y; Ws[lk + 2][lr] = w4.z; Ws[lk + 3][lr] = w4.w;
        __syncthreads();
#pragma unroll
        for (int kk = 0; kk < 16; ++kk) {
            const float4 av = *(const float4*)&As[kk][ty * 4];
            const float4 wv = *(const float4*)&Ws[kk][tx * 4];
            const float a_[4] = {av.x, av.y, av.z, av.w};
            const float w_[4] = {wv.x, wv.y, wv.z, wv.w};
#pragma unroll
            for (int i = 0; i < 4; ++i)
#pragma unroll
                for (int j = 0; j < 4; ++j)
                    acc[i][j] = fmaf(a_[i], w_[j], acc[i][j]);
        }
    }
    const float4 bv = *(const float4*)(bias + bn + tx * 4);
#pragma unroll
    for (int i = 0; i < 4; ++i) {
        const size_t m = (size_t)(bm + ty * 4 + i);
        float4 o;
        o.x = acc[i][0] + bv.x; o.y = acc[i][1] + bv.y;
        o.z = acc[i][2] + bv.z; o.w = acc[i][3] + bv.w;
        *(float4*)(C + m * N + bn + tx * 4) = o;
    }
}

// ---------------------------------------------------------------------------
// Grid index from loc_orig
// ---------------------------------------------------------------------------
__global__ void grid_idx_k(const float* __restrict__ loc, int* __restrict__ idx_hw)
{
    const int p = blockIdx.x * 256 + threadIdx.x;
    if (p >= kPTS) return;
    float lx = loc[(size_t)p * 2 + 0];
    float ly = loc[(size_t)p * 2 + 1];
    lx = fminf(fmaxf(lx, -1.f), 1.f) * 0.5f + 0.5f;
    ly = fminf(fmaxf(ly, -1.f), 1.f) * 0.5f + 0.5f;
    int gx = (int)rintf(lx * (float)(kW - 1)); gx = min(max(gx, 0), kW - 1);
    int gy = (int)rintf(ly * (float)(kH - 1)); gy = min(max(gy, 0), kH - 1);
    idx_hw[p] = gy * kW + gx;
}

// ---------------------------------------------------------------------------
// CSR build: count -> exclusive scan (3 kernels) -> fill
// ---------------------------------------------------------------------------
__global__ void count_k(const int* __restrict__ iagg, const int* __restrict__ ihw,
                        int* __restrict__ cnt_cell, int* __restrict__ cnt_tok)
{
    const int p = blockIdx.x * 256 + threadIdx.x;
    if (p >= kPTS) return;
    const int b = p / kN0;
    atomicAdd(cnt_cell + b * kHW + ihw[p], 1);
    atomicAdd(cnt_tok  + b * kN  + iagg[p], 1);
}

__global__ __launch_bounds__(256) void scan1_k(const int* __restrict__ cnt,
                                               int* __restrict__ off, int* __restrict__ bsum)
{
    __shared__ int sh[256];
    const int t = threadIdx.x;
    const int i = blockIdx.x * 256 + t;
    const int v = cnt[i];
    sh[t] = v; __syncthreads();
#pragma unroll
    for (int o = 1; o < 256; o <<= 1) {
        const int tmp = (t >= o) ? sh[t - o] : 0;
        __syncthreads();
        sh[t] += tmp;
        __syncthreads();
    }
    off[i] = sh[t] - v;
    if (t == 255) bsum[blockIdx.x] = sh[255];
}

__global__ __launch_bounds__(256) void scan2_k(int* __restrict__ bsum, int nb)
{
    __shared__ int sh[256];
    const int t = threadIdx.x;
    const int v = (t < nb) ? bsum[t] : 0;
    sh[t] = v; __syncthreads();
#pragma unroll
    for (int o = 1; o < 256; o <<= 1) {
        const int tmp = (t >= o) ? sh[t - o] : 0;
        __syncthreads();
        sh[t] += tmp;
        __syncthreads();
    }
    if (t < nb) bsum[t] = sh[t] - v;
}

__global__ __launch_bounds__(256) void scan3_k(int* __restrict__ off, int* __restrict__ fill,
                                               const int* __restrict__ bsum, int n, int total)
{
    const int i = blockIdx.x * 256 + threadIdx.x;
    const int v = off[i] + bsum[blockIdx.x];
    off[i] = v; fill[i] = v;
    if (i == 0) off[n] = total;
}

__global__ void fill_k(const int* __restrict__ iagg, const int* __restrict__ ihw,
                       const float* __restrict__ aw,
                       int* __restrict__ fill_cell, int* __restrict__ fill_tok,
                       int* __restrict__ tok_by_cell, int* __restrict__ cell_by_tok,
                       float* __restrict__ w_by_tok)
{
    const int p = blockIdx.x * 256 + threadIdx.x;
    if (p >= kPTS) return;
    const int b = p / kN0;
    const int tokrow = b * kN + iagg[p];
    const int cell   = b * kHW + ihw[p];
    const int cpos = atomicAdd(fill_cell + cell, 1);
    tok_by_cell[cpos] = tokrow;
    const int tpos = atomicAdd(fill_tok + tokrow, 1);
    cell_by_tok[tpos] = cell;
    w_by_tok[tpos] = aw[p];
}

// ---------------------------------------------------------------------------
// Column stats (per-channel sum/sumsq)
// ---------------------------------------------------------------------------
__global__ __launch_bounds__(512) void colstats512_k(
    const float* __restrict__ X, float* __restrict__ gsum, float* __restrict__ gsq,
    int rows_per_blk)
{
    const int c = threadIdx.x;
    const int r0 = blockIdx.x * rows_per_blk;
    float s = 0.f, q = 0.f;
    for (int r = 0; r < rows_per_blk; ++r) {
        const float v = X[(size_t)(r0 + r) * kCHID + c];
        s += v; q += v * v;
    }
    atomicAdd(&gsum[c], s);
    atomicAdd(&gsq[c], q);
}

__global__ __launch_bounds__(256) void colstats128_k(
    const float* __restrict__ X, float* __restrict__ gsum, float* __restrict__ gsq,
    int rows_per_blk)
{
    const int c = threadIdx.x & 127;
    const int rr = threadIdx.x >> 7;
    const int r0 = blockIdx.x * rows_per_blk;
    float s = 0.f, q = 0.f;
    for (int r = rr; r < rows_per_blk; r += 2) {
        const float v = X[(size_t)(r0 + r) * kCOUT + c];
        s += v; q += v * v;
    }
    atomicAdd(&gsum[c], s);
    atomicAdd(&gsq[c], q);
}

__global__ void bn_coef_k(const float* __restrict__ gsum, const float* __restrict__ gsq,
                          const float* __restrict__ g, const float* __restrict__ bb,
                          float* __restrict__ scale, float* __restrict__ shift,
                          int C, float invn)
{
    const int c = blockIdx.x * blockDim.x + threadIdx.x;
    if (c >= C) return;
    const float m = gsum[c] * invn;
    const float v = fmaxf(gsq[c] * invn - m * m, 0.f);
    const float sc = g[c] * rsqrtf(v + kBEPS);
    scale[c] = sc;
    shift[c] = bb[c] - m * sc;
}

__global__ __launch_bounds__(256) void bn_act_k(
    const float* __restrict__ in, float* __restrict__ out,
    const float* __restrict__ scale, const float* __restrict__ shift,
    size_t n4, int c4div)
{
    const size_t stride = (size_t)gridDim.x * blockDim.x;
    for (size_t i = (size_t)blockIdx.x * blockDim.x + threadIdx.x; i < n4; i += stride) {
        const int c0 = (int)(i % (size_t)c4div) * 4;
        float4 v = ((const float4*)in)[i];
        const float4 sc = *(const float4*)(scale + c0);
        const float4 sh = *(const float4*)(shift + c0);
        v.x = gelu_f(fmaf(v.x, sc.x, sh.x));
        v.y = gelu_f(fmaf(v.y, sc.y, sh.y));
        v.z = gelu_f(fmaf(v.z, sc.z, sh.z));
        v.w = gelu_f(fmaf(v.w, sc.w, sh.w));
        ((float4*)out)[i] = v;
    }
}

// ---------------------------------------------------------------------------
// token2map gather: one wave per cell; normalized output. Empty cells skipped.
// ---------------------------------------------------------------------------
__global__ __launch_bounds__(256) void gather_map_k(
    const float* __restrict__ hbuf, const int* __restrict__ off,
    const int* __restrict__ toklist, float* __restrict__ smap)
{
    const int lane = threadIdx.x & 63;
    const int cell = blockIdx.x * 4 + (threadIdx.x >> 6);
    const int s = off[cell], e = off[cell + 1];
    if (s == e) return;
    float4 a0 = {0.f, 0.f, 0.f, 0.f}, a1 = {0.f, 0.f, 0.f, 0.f};
    for (int j = s; j < e; ++j) {
        const float* row = hbuf + (size_t)toklist[j] * kCHID + lane * 8;
        const float4 v0 = ((const float4*)row)[0];
        const float4 v1 = ((const float4*)row)[1];
        a0.x += v0.x; a0.y += v0.y; a0.z += v0.z; a0.w += v0.w;
        a1.x += v1.x; a1.y += v1.y; a1.z += v1.z; a1.w += v1.w;
    }
    const float sc = 1.f / ((float)(e - s) + kEPS);
    float* dst = smap + (size_t)cell * kCHID + lane * 8;
    ((float4*)dst)[0] = make_float4(a0.x * sc, a0.y * sc, a0.z * sc, a0.w * sc);
    ((float4*)dst)[1] = make_float4(a1.x * sc, a1.y * sc, a1.z * sc, a1.w * sc);
}

// ---------------------------------------------------------------------------
// Depthwise 3x3 conv over normalized NHWC map; empties via off_cell diffs.
// ---------------------------------------------------------------------------
__global__ __launch_bounds__(256) void dwconv_k(
    const float* __restrict__ smap, const int* __restrict__ off,
    const float* __restrict__ wdw, const float* __restrict__ bdw,
    float* __restrict__ outm)
{
    const size_t i = (size_t)blockIdx.x * 256 + threadIdx.x;   // over B*HW*128
    const int c4 = (int)(i & 127);
    const int cb = (int)(i >> 7);
    const int cell = cb % kHW;
    const int b = cb / kHW;
    const int gbase = b * kHW;
    if (off[gbase + cell + 1] - off[gbase + cell] == 0) return; // wave-uniform
    const int y = cell / kW, x = cell % kW;
    const int c0 = c4 * 4;
    const float4 bv = *(const float4*)(bdw + c0);
    float a0 = bv.x, a1 = bv.y, a2 = bv.z, a3 = bv.w;
#pragma unroll
    for (int dy = 0; dy < 3; ++dy) {
        const int yy = y + dy - 1;
        if ((unsigned)yy >= (unsigned)kH) continue;
#pragma unroll
        for (int dx = 0; dx < 3; ++dx) {
            const int xx = x + dx - 1;
            if ((unsigned)xx >= (unsigned)kW) continue;
            const int gn = gbase + yy * kW + xx;
            if (off[gn + 1] - off[gn] == 0) continue;
            const float4 v = *(const float4*)(smap + (size_t)gn * kCHID + c0);
            const int wo = dy * 3 + dx;
            a0 = fmaf(wdw[(c0 + 0) * 9 + wo], v.x, a0);
            a1 = fmaf(wdw[(c0 + 1) * 9 + wo], v.y, a1);
            a2 = fmaf(wdw[(c0 + 2) * 9 + wo], v.z, a2);
            a3 = fmaf(wdw[(c0 + 3) * 9 + wo], v.w, a3);
        }
    }
    *(float4*)(outm + (size_t)(gbase + cell) * kCHID + c0) = make_float4(a0, a1, a2, a3);
}

// ---------------------------------------------------------------------------
// map2token gather + fused skip: h2 = hpost*dws + num/(den+eps), in place.
// ---------------------------------------------------------------------------
__global__ __launch_bounds__(256) void gather_tok_k(
    const float* __restrict__ convo, const int* __restrict__ off,
    const int* __restrict__ celllist, const float* __restrict__ wlist,
    const float* __restrict__ dws, float* __restrict__ hbuf)
{
    const int lane = threadIdx.x & 63;
    const int t = blockIdx.x * 4 + (threadIdx.x >> 6);
    const int s = off[t], e = off[t + 1];
    float4 a0 = {0.f, 0.f, 0.f, 0.f}, a1 = {0.f, 0.f, 0.f, 0.f};
    float den = 0.f;
    for (int j = s; j < e; ++j) {
        const float w = wlist[j];
        den += w;
        const float* row = convo + (size_t)celllist[j] * kCHID + lane * 8;
        const float4 v0 = ((const float4*)row)[0];
        const float4 v1 = ((const float4*)row)[1];
        a0.x = fmaf(w, v0.x, a0.x); a0.y = fmaf(w, v0.y, a0.y);
        a0.z = fmaf(w, v0.z, a0.z); a0.w = fmaf(w, v0.w, a0.w);
        a1.x = fmaf(w, v1.x, a1.x); a1.y = fmaf(w, v1.y, a1.y);
        a1.z = fmaf(w, v1.z, a1.z); a1.w = fmaf(w, v1.w, a1.w);
    }
    const float r = 1.f / (den + kEPS);
    float* hrow = hbuf + (size_t)t * kCHID + lane * 8;
    const float4 h0 = ((const float4*)hrow)[0];
    const float4 h1 = ((const float4*)hrow)[1];
    const float4 d0 = *(const float4*)(dws + lane * 8);
    const float4 d1 = *(const float4*)(dws + lane * 8 + 4);
    float4 o0, o1;
    o0.x = fmaf(h0.x, d0.x, a0.x * r); o0.y = fmaf(h0.y, d0.y, a0.y * r);
    o0.z = fmaf(h0.z, d0.z, a0.z * r); o0.w = fmaf(h0.w, d0.w, a0.w * r);
    o1.x = fmaf(h1.x, d1.x, a1.x * r); o1.y = fmaf(h1.y, d1.y, a1.y * r);
    o1.z = fmaf(h1.z, d1.z, a1.z * r); o1.w = fmaf(h1.w, d1.w, a1.w * r);
    ((float4*)hrow)[0] = o0;
    ((float4*)hrow)[1] = o1;
}

// ---------------------------------------------------------------------------
extern "C" void kernel_launch(void* const* d_in, const int* in_sizes, int n_in,
                              void* d_out, int out_size, void* d_ws, size_t ws_size,
                              hipStream_t stream)
{
    (void)in_sizes; (void)n_in; (void)out_size; (void)ws_size;
    const float* x    = (const float*)d_in[0];
    const float* loc  = (const float*)d_in[1];
    const int*   iagg = (const int*)  d_in[2];
    const float* aw   = (const float*)d_in[3];
    const float* fc1w = (const float*)d_in[4];
    const float* fc1b = (const float*)d_in[5];
    const float* g1   = (const float*)d_in[6];
    const float* b1   = (const float*)d_in[7];
    const float* dww  = (const float*)d_in[8];
    const float* dwb  = (const float*)d_in[9];
    const float* dwsw = (const float*)d_in[10];
    const float* g2   = (const float*)d_in[11];
    const float* b2   = (const float*)d_in[12];
    const float* fc2w = (const float*)d_in[13];
    const float* fc2b = (const float*)d_in[14];
    const float* g3   = (const float*)d_in[15];
    const float* b3   = (const float*)d_in[16];
    float* outp = (float*)d_out;

    float* ws = (float*)d_ws;
    // --- zeroed region: BN stats + CSR counters ---
    float* gsum1 = ws + 0;           // 512
    float* gsq1  = ws + 512;
    float* gsum2 = ws + 1024;
    float* gsq2  = ws + 1536;
    float* gsum3 = ws + 2048;        // 128
    float* gsq3  = ws + 2176;        // 128
    int* cnt_cell = (int*)(ws + 2304);     // 50176
    int* cnt_tok  = cnt_cell + kBHW;       // 12544
    const size_t zero_bytes = (2304ull + kBHW + kROWS) * 4;
    // --- non-zeroed ---
    int* off_cell  = cnt_tok + kROWS;      // 50180 (padded)
    int* off_tok   = off_cell + 50180;     // 12548 (padded)
    int* fill_cell = off_tok + 12548;      // 50176
    int* fill_tok  = fill_cell + kBHW;     // 12544
    int* bsum      = fill_tok + kROWS;     // 256
    int* ihw       = bsum + 256;           // 50176
    int* tok_by_cell = ihw + kPTS;         // 50176
    int* cell_by_tok = tok_by_cell + kPTS; // 50176
    float* w_by_tok  = (float*)(cell_by_tok + kPTS); // 50176
    float* scale1 = w_by_tok + kPTS;
    float* shift1 = scale1 + 512;
    float* scale2 = shift1 + 512;
    float* shift2 = scale2 + 512;
    float* scale3 = shift2 + 512;
    float* shift3 = scale3 + 128;
    float* hbuf   = shift3 + 128;                       // 6,422,528 (h -> h2 -> h3)
    float* smap   = hbuf + (size_t)kROWS * kCHID;       // 25,690,112
    float* convo  = smap + (size_t)kBHW * kCHID;        // 25,690,112
    float* out3   = smap;                               // alias: smap dead after dwconv

    hipMemsetAsync(ws, 0, zero_bytes, stream);

    // fc1
    gemm_nt_bias<<<dim3(kROWS / 64, kCHID / 64), 256, 0, stream>>>(
        x, fc1w, fc1b, hbuf, kROWS, kCHID, kCIN);

    // CSR build
    grid_idx_k<<<kPTS / 256, 256, 0, stream>>>(loc, ihw);
    count_k<<<kPTS / 256, 256, 0, stream>>>(iagg, ihw, cnt_cell, cnt_tok);
    scan1_k<<<kBHW / 256, 256, 0, stream>>>(cnt_cell, off_cell, bsum);
    scan2_k<<<1, 256, 0, stream>>>(bsum, kBHW / 256);
    scan3_k<<<kBHW / 256, 256, 0, stream>>>(off_cell, fill_cell, bsum, kBHW, kPTS);
    scan1_k<<<kROWS / 256, 256, 0, stream>>>(cnt_tok, off_tok, bsum);
    scan2_k<<<1, 256, 0, stream>>>(bsum, kROWS / 256);
    scan3_k<<<kROWS / 256, 256, 0, stream>>>(off_tok, fill_tok, bsum, kROWS, kPTS);
    fill_k<<<kPTS / 256, 256, 0, stream>>>(iagg, ihw, aw, fill_cell, fill_tok,
                                           tok_by_cell, cell_by_tok, w_by_tok);

    // BN1 + GELU
    colstats512_k<<<392, 512, 0, stream>>>(hbuf, gsum1, gsq1, 32);
    bn_coef_k<<<1, 512, 0, stream>>>(gsum1, gsq1, g1, b1, scale1, shift1, kCHID, 1.f / kROWS);
    bn_act_k<<<2048, 256, 0, stream>>>(hbuf, hbuf, scale1, shift1,
                                       (size_t)kROWS * kCHID / 4, kCHID / 4);

    // token -> map -> dwconv -> token (+fused skip)
    gather_map_k<<<kBHW / 4, 256, 0, stream>>>(hbuf, off_cell, tok_by_cell, smap);
    dwconv_k<<<(kB * kHW * (kCHID / 4)) / 256, 256, 0, stream>>>(smap, off_cell, dww, dwb, convo);
    gather_tok_k<<<kROWS / 4, 256, 0, stream>>>(convo, off_tok, cell_by_tok, w_by_tok,
                                                dwsw, hbuf);

    // BN2 + GELU
    colstats512_k<<<392, 512, 0, stream>>>(hbuf, gsum2, gsq2, 32);
    bn_coef_k<<<1, 512, 0, stream>>>(gsum2, gsq2, g2, b2, scale2, shift2, kCHID, 1.f / kROWS);
    bn_act_k<<<2048, 256, 0, stream>>>(hbuf, hbuf, scale2, shift2,
                                       (size_t)kROWS * kCHID / 4, kCHID / 4);

    // fc2
    gemm_nt_bias<<<dim3(kROWS / 64, kCOUT / 64), 256, 0, stream>>>(
        hbuf, fc2w, fc2b, out3, kROWS, kCOUT, kCHID);

    // BN3 + GELU -> out
    colstats128_k<<<392, 256, 0, stream>>>(out3, gsum3, gsq3, 32);
    bn_coef_k<<<1, 128, 0, stream>>>(gsum3, gsq3, g3, b3, scale3, shift3, kCOUT, 1.f / kROWS);
    bn_act_k<<<2048, 256, 0, stream>>>(out3, outp, scale3, shift3,
                                       (size_t)kROWS * kCOUT / 4, kCOUT / 4);
}

// Round 3
// 303.554 us; speedup vs baseline: 2.1005x; 1.1910x over previous
//
#include <hip/hip_runtime.h>
#include <math.h>

// Problem constants (fixed by the reference)
constexpr int kB    = 4;
constexpr int kN    = 3136;    // tokens per batch
constexpr int kN0   = 12544;   // points per batch
constexpr int kH    = 112, kW = 112;
constexpr int kHW   = kH * kW;          // 12544
constexpr int kCIN  = 128;
constexpr int kCHID = 512;
constexpr int kCOUT = 128;
constexpr int kROWS = kB * kN;          // 12544 token rows total
constexpr int kPTS  = kB * kN0;         // 50176 points total
constexpr int kBHW  = kB * kHW;         // 50176 cells total
constexpr float kEPS  = 1e-6f;
constexpr float kBEPS = 1e-5f;

__device__ __forceinline__ float gelu_f(float x) {
    return 0.5f * x * (1.0f + erff(x * 0.70710678118654752440f));
}

// ---------------------------------------------------------------------------
// GEMM: C[M,N] = A[M,K] * W[N,K]^T + bias[N]
// ---------------------------------------------------------------------------
__global__ __launch_bounds__(256) void gemm_nt_bias(
    const float* __restrict__ A, const float* __restrict__ Wm,
    const float* __restrict__ bias, float* __restrict__ C,
    int M, int N, int K)
{
    __shared__ float As[16][64];
    __shared__ float Ws[16][64];
    const int bm = blockIdx.x * 64, bn = blockIdx.y * 64;
    const int tid = threadIdx.x;
    const int tx = tid & 15, ty = tid >> 4;
    const int lr = tid >> 2;
    const int lk = (tid & 3) << 2;
    float acc[4][4] = {};
    for (int k0 = 0; k0 < K; k0 += 16) {
        const float4 a4 = *(const float4*)(A  + (size_t)(bm + lr) * K + (k0 + lk));
        const float4 w4 = *(const float4*)(Wm + (size_t)(bn + lr) * K + (k0 + lk));
        __syncthreads();
        As[lk + 0][lr] = a4.x; As[lk + 1][lr] = a4.y; As[lk + 2][lr] = a4.z; As[lk + 3][lr] = a4.w;
        Ws[lk + 0][lr] = w4.x; Ws[lk + 1][lr] = w4.y; Ws[lk + 2][lr] = w4.z; Ws[lk + 3][lr] = w4.w;
        __syncthreads();
#pragma unroll
        for (int kk = 0; kk < 16; ++kk) {
            const float4 av = *(const float4*)&As[kk][ty * 4];
            const float4 wv = *(const float4*)&Ws[kk][tx * 4];
            const float a_[4] = {av.x, av.y, av.z, av.w};
            const float w_[4] = {wv.x, wv.y, wv.z, wv.w};
#pragma unroll
            for (int i = 0; i < 4; ++i)
#pragma unroll
                for (int j = 0; j < 4; ++j)
                    acc[i][j] = fmaf(a_[i], w_[j], acc[i][j]);
        }
    }
    const float4 bv = *(const float4*)(bias + bn + tx * 4);
#pragma unroll
    for (int i = 0; i < 4; ++i) {
        const size_t m = (size_t)(bm + ty * 4 + i);
        float4 o;
        o.x = acc[i][0] + bv.x; o.y = acc[i][1] + bv.y;
        o.z = acc[i][2] + bv.z; o.w = acc[i][3] + bv.w;
        *(float4*)(C + m * N + bn + tx * 4) = o;
    }
}

// ---------------------------------------------------------------------------
// Grid index from loc_orig
// ---------------------------------------------------------------------------
__global__ void grid_idx_k(const float* __restrict__ loc, int* __restrict__ idx_hw)
{
    const int p = blockIdx.x * 256 + threadIdx.x;
    if (p >= kPTS) return;
    float lx = loc[(size_t)p * 2 + 0];
    float ly = loc[(size_t)p * 2 + 1];
    lx = fminf(fmaxf(lx, -1.f), 1.f) * 0.5f + 0.5f;
    ly = fminf(fmaxf(ly, -1.f), 1.f) * 0.5f + 0.5f;
    int gx = (int)rintf(lx * (float)(kW - 1)); gx = min(max(gx, 0), kW - 1);
    int gy = (int)rintf(ly * (float)(kH - 1)); gy = min(max(gy, 0), kH - 1);
    idx_hw[p] = gy * kW + gx;
}

// ---------------------------------------------------------------------------
// Depthwise weight transpose: [512][9] -> [9][512]
// ---------------------------------------------------------------------------
__global__ void wtrans_k(const float* __restrict__ dww, float* __restrict__ wT)
{
    const int i = blockIdx.x * 256 + threadIdx.x;
    if (i >= 9 * 512) return;
    const int tap = i / 512, c = i % 512;
    wT[i] = dww[c * 9 + tap];
}

// ---------------------------------------------------------------------------
// CSR build: count -> exclusive scan (3 kernels) -> fill
// ---------------------------------------------------------------------------
__global__ void count_k(const int* __restrict__ iagg, const int* __restrict__ ihw,
                        int* __restrict__ cnt_cell, int* __restrict__ cnt_tok)
{
    const int p = blockIdx.x * 256 + threadIdx.x;
    if (p >= kPTS) return;
    const int b = p / kN0;
    atomicAdd(cnt_cell + b * kHW + ihw[p], 1);
    atomicAdd(cnt_tok  + b * kN  + iagg[p], 1);
}

__global__ __launch_bounds__(256) void scan1_k(const int* __restrict__ cnt,
                                               int* __restrict__ off, int* __restrict__ bsum)
{
    __shared__ int sh[256];
    const int t = threadIdx.x;
    const int i = blockIdx.x * 256 + t;
    const int v = cnt[i];
    sh[t] = v; __syncthreads();
#pragma unroll
    for (int o = 1; o < 256; o <<= 1) {
        const int tmp = (t >= o) ? sh[t - o] : 0;
        __syncthreads();
        sh[t] += tmp;
        __syncthreads();
    }
    off[i] = sh[t] - v;
    if (t == 255) bsum[blockIdx.x] = sh[255];
}

__global__ __launch_bounds__(256) void scan2_k(int* __restrict__ bsum, int nb)
{
    __shared__ int sh[256];
    const int t = threadIdx.x;
    const int v = (t < nb) ? bsum[t] : 0;
    sh[t] = v; __syncthreads();
#pragma unroll
    for (int o = 1; o < 256; o <<= 1) {
        const int tmp = (t >= o) ? sh[t - o] : 0;
        __syncthreads();
        sh[t] += tmp;
        __syncthreads();
    }
    if (t < nb) bsum[t] = sh[t] - v;
}

__global__ __launch_bounds__(256) void scan3_k(int* __restrict__ off, int* __restrict__ fill,
                                               const int* __restrict__ bsum, int n, int total)
{
    const int i = blockIdx.x * 256 + threadIdx.x;
    const int v = off[i] + bsum[blockIdx.x];
    off[i] = v; fill[i] = v;
    if (i == 0) off[n] = total;
}

__global__ void fill_k(const int* __restrict__ iagg, const int* __restrict__ ihw,
                       const float* __restrict__ aw,
                       int* __restrict__ fill_cell, int* __restrict__ fill_tok,
                       int* __restrict__ tok_by_cell, int* __restrict__ cell_by_tok,
                       float* __restrict__ w_by_tok)
{
    const int p = blockIdx.x * 256 + threadIdx.x;
    if (p >= kPTS) return;
    const int b = p / kN0;
    const int tokrow = b * kN + iagg[p];
    const int cell   = b * kHW + ihw[p];
    const int cpos = atomicAdd(fill_cell + cell, 1);
    tok_by_cell[cpos] = tokrow;
    const int tpos = atomicAdd(fill_tok + tokrow, 1);
    cell_by_tok[tpos] = cell;
    w_by_tok[tpos] = aw[p];
}

// ---------------------------------------------------------------------------
// Column stats (per-channel sum/sumsq)
// ---------------------------------------------------------------------------
__global__ __launch_bounds__(512) void colstats512_k(
    const float* __restrict__ X, float* __restrict__ gsum, float* __restrict__ gsq,
    int rows_per_blk)
{
    const int c = threadIdx.x;
    const int r0 = blockIdx.x * rows_per_blk;
    float s = 0.f, q = 0.f;
    for (int r = 0; r < rows_per_blk; ++r) {
        const float v = X[(size_t)(r0 + r) * kCHID + c];
        s += v; q += v * v;
    }
    atomicAdd(&gsum[c], s);
    atomicAdd(&gsq[c], q);
}

__global__ __launch_bounds__(256) void colstats128_k(
    const float* __restrict__ X, float* __restrict__ gsum, float* __restrict__ gsq,
    int rows_per_blk)
{
    const int c = threadIdx.x & 127;
    const int rr = threadIdx.x >> 7;
    const int r0 = blockIdx.x * rows_per_blk;
    float s = 0.f, q = 0.f;
    for (int r = rr; r < rows_per_blk; r += 2) {
        const float v = X[(size_t)(r0 + r) * kCOUT + c];
        s += v; q += v * v;
    }
    atomicAdd(&gsum[c], s);
    atomicAdd(&gsq[c], q);
}

__global__ void bn_coef_k(const float* __restrict__ gsum, const float* __restrict__ gsq,
                          const float* __restrict__ g, const float* __restrict__ bb,
                          float* __restrict__ scale, float* __restrict__ shift,
                          int C, float invn)
{
    const int c = blockIdx.x * blockDim.x + threadIdx.x;
    if (c >= C) return;
    const float m = gsum[c] * invn;
    const float v = fmaxf(gsq[c] * invn - m * m, 0.f);
    const float sc = g[c] * rsqrtf(v + kBEPS);
    scale[c] = sc;
    shift[c] = bb[c] - m * sc;
}

__global__ __launch_bounds__(256) void bn_act_k(
    const float* __restrict__ in, float* __restrict__ out,
    const float* __restrict__ scale, const float* __restrict__ shift,
    size_t n4, int c4div)
{
    const size_t stride = (size_t)gridDim.x * blockDim.x;
    for (size_t i = (size_t)blockIdx.x * blockDim.x + threadIdx.x; i < n4; i += stride) {
        const int c0 = (int)(i % (size_t)c4div) * 4;
        float4 v = ((const float4*)in)[i];
        const float4 sc = *(const float4*)(scale + c0);
        const float4 sh = *(const float4*)(shift + c0);
        v.x = gelu_f(fmaf(v.x, sc.x, sh.x));
        v.y = gelu_f(fmaf(v.y, sc.y, sh.y));
        v.z = gelu_f(fmaf(v.z, sc.z, sh.z));
        v.w = gelu_f(fmaf(v.w, sc.w, sh.w));
        ((float4*)out)[i] = v;
    }
}

// ---------------------------------------------------------------------------
// token2map gather: one wave per cell; normalized output. Empty cells -> 0
// (exact: reference conv input at empty cells is 0/(0+eps) = 0).
// ---------------------------------------------------------------------------
__global__ __launch_bounds__(256) void gather_map_k(
    const float* __restrict__ hbuf, const int* __restrict__ off,
    const int* __restrict__ toklist, float* __restrict__ smap)
{
    const int lane = threadIdx.x & 63;
    const int cell = blockIdx.x * 4 + (threadIdx.x >> 6);
    const int s = off[cell], e = off[cell + 1];
    float4 a0 = {0.f, 0.f, 0.f, 0.f}, a1 = {0.f, 0.f, 0.f, 0.f};
    for (int j = s; j < e; ++j) {
        const float* row = hbuf + (size_t)toklist[j] * kCHID + lane * 8;
        const float4 v0 = ((const float4*)row)[0];
        const float4 v1 = ((const float4*)row)[1];
        a0.x += v0.x; a0.y += v0.y; a0.z += v0.z; a0.w += v0.w;
        a1.x += v1.x; a1.y += v1.y; a1.z += v1.z; a1.w += v1.w;
    }
    const float sc = 1.f / ((float)(e - s) + kEPS);
    float* dst = smap + (size_t)cell * kCHID + lane * 8;
    ((float4*)dst)[0] = make_float4(a0.x * sc, a0.y * sc, a0.z * sc, a0.w * sc);
    ((float4*)dst)[1] = make_float4(a1.x * sc, a1.y * sc, a1.z * sc, a1.w * sc);
}

// ---------------------------------------------------------------------------
// Depthwise 3x3, NHWC, zero-filled map: no neighbor emptiness checks.
// Each thread: 2x2 output cells x 4 channels. 16 tap loads + 9 weight float4.
// ---------------------------------------------------------------------------
__global__ __launch_bounds__(256) void dwconv_k(
    const float* __restrict__ smap, const int* __restrict__ cnt,
    const float* __restrict__ wT, const float* __restrict__ bdw,
    float* __restrict__ outm)
{
    constexpr int kTX = kW / 2;            // 56 tiles per row
    const int c4 = threadIdx.x & 127;
    const int w  = blockIdx.x * 2 + (threadIdx.x >> 7);
    const int b   = w / (kTX * kTX);
    const int rem = w % (kTX * kTX);
    const int ty = rem / kTX, tx = rem % kTX;
    const int y0 = ty * 2, x0 = tx * 2;
    const int gbase = b * kHW;
    const int c0 = c4 * 4;

    const int cell00 = gbase + y0 * kW + x0;
    const int n00 = cnt[cell00],       n01 = cnt[cell00 + 1];
    const int n10 = cnt[cell00 + kW],  n11 = cnt[cell00 + kW + 1];
    if ((n00 | n01 | n10 | n11) == 0) return;

    float4 wv[9];
#pragma unroll
    for (int t = 0; t < 9; ++t) wv[t] = *(const float4*)(wT + t * kCHID + c0);
    const float4 bv = *(const float4*)(bdw + c0);
    float4 acc[2][2] = {{bv, bv}, {bv, bv}};

#pragma unroll
    for (int dy = 0; dy < 4; ++dy) {
        const int yy = y0 - 1 + dy;
        if ((unsigned)yy >= (unsigned)kH) continue;
#pragma unroll
        for (int dx = 0; dx < 4; ++dx) {
            const int xx = x0 - 1 + dx;
            if ((unsigned)xx >= (unsigned)kW) continue;
            const float4 v = *(const float4*)(smap + (size_t)(gbase + yy * kW + xx) * kCHID + c0);
#pragma unroll
            for (int cy = 0; cy < 2; ++cy) {
                const int wy = dy - cy;          // tap row for this output
                if ((unsigned)wy >= 3u) continue;
#pragma unroll
                for (int cx = 0; cx < 2; ++cx) {
                    const int wx = dx - cx;
                    if ((unsigned)wx >= 3u) continue;
                    const float4 wq = wv[wy * 3 + wx];
                    acc[cy][cx].x = fmaf(wq.x, v.x, acc[cy][cx].x);
                    acc[cy][cx].y = fmaf(wq.y, v.y, acc[cy][cx].y);
                    acc[cy][cx].z = fmaf(wq.z, v.z, acc[cy][cx].z);
                    acc[cy][cx].w = fmaf(wq.w, v.w, acc[cy][cx].w);
                }
            }
        }
    }
    if (n00) *(float4*)(outm + (size_t)cell00 * kCHID + c0)            = acc[0][0];
    if (n01) *(float4*)(outm + (size_t)(cell00 + 1) * kCHID + c0)      = acc[0][1];
    if (n10) *(float4*)(outm + (size_t)(cell00 + kW) * kCHID + c0)     = acc[1][0];
    if (n11) *(float4*)(outm + (size_t)(cell00 + kW + 1) * kCHID + c0) = acc[1][1];
}

// ---------------------------------------------------------------------------
// map2token gather + fused skip: h2 = hpost*dws + num/(den+eps), in place.
// ---------------------------------------------------------------------------
__global__ __launch_bounds__(256) void gather_tok_k(
    const float* __restrict__ convo, const int* __restrict__ off,
    const int* __restrict__ celllist, const float* __restrict__ wlist,
    const float* __restrict__ dws, float* __restrict__ hbuf)
{
    const int lane = threadIdx.x & 63;
    const int t = blockIdx.x * 4 + (threadIdx.x >> 6);
    const int s = off[t], e = off[t + 1];
    float4 a0 = {0.f, 0.f, 0.f, 0.f}, a1 = {0.f, 0.f, 0.f, 0.f};
    float den = 0.f;
    for (int j = s; j < e; ++j) {
        const float w = wlist[j];
        den += w;
        const float* row = convo + (size_t)celllist[j] * kCHID + lane * 8;
        const float4 v0 = ((const float4*)row)[0];
        const float4 v1 = ((const float4*)row)[1];
        a0.x = fmaf(w, v0.x, a0.x); a0.y = fmaf(w, v0.y, a0.y);
        a0.z = fmaf(w, v0.z, a0.z); a0.w = fmaf(w, v0.w, a0.w);
        a1.x = fmaf(w, v1.x, a1.x); a1.y = fmaf(w, v1.y, a1.y);
        a1.z = fmaf(w, v1.z, a1.z); a1.w = fmaf(w, v1.w, a1.w);
    }
    const float r = 1.f / (den + kEPS);
    float* hrow = hbuf + (size_t)t * kCHID + lane * 8;
    const float4 h0 = ((const float4*)hrow)[0];
    const float4 h1 = ((const float4*)hrow)[1];
    const float4 d0 = *(const float4*)(dws + lane * 8);
    const float4 d1 = *(const float4*)(dws + lane * 8 + 4);
    float4 o0, o1;
    o0.x = fmaf(h0.x, d0.x, a0.x * r); o0.y = fmaf(h0.y, d0.y, a0.y * r);
    o0.z = fmaf(h0.z, d0.z, a0.z * r); o0.w = fmaf(h0.w, d0.w, a0.w * r);
    o1.x = fmaf(h1.x, d1.x, a1.x * r); o1.y = fmaf(h1.y, d1.y, a1.y * r);
    o1.z = fmaf(h1.z, d1.z, a1.z * r); o1.w = fmaf(h1.w, d1.w, a1.w * r);
    ((float4*)hrow)[0] = o0;
    ((float4*)hrow)[1] = o1;
}

// ---------------------------------------------------------------------------
extern "C" void kernel_launch(void* const* d_in, const int* in_sizes, int n_in,
                              void* d_out, int out_size, void* d_ws, size_t ws_size,
                              hipStream_t stream)
{
    (void)in_sizes; (void)n_in; (void)out_size; (void)ws_size;
    const float* x    = (const float*)d_in[0];
    const float* loc  = (const float*)d_in[1];
    const int*   iagg = (const int*)  d_in[2];
    const float* aw   = (const float*)d_in[3];
    const float* fc1w = (const float*)d_in[4];
    const float* fc1b = (const float*)d_in[5];
    const float* g1   = (const float*)d_in[6];
    const float* b1   = (const float*)d_in[7];
    const float* dww  = (const float*)d_in[8];
    const float* dwb  = (const float*)d_in[9];
    const float* dwsw = (const float*)d_in[10];
    const float* g2   = (const float*)d_in[11];
    const float* b2   = (const float*)d_in[12];
    const float* fc2w = (const float*)d_in[13];
    const float* fc2b = (const float*)d_in[14];
    const float* g3   = (const float*)d_in[15];
    const float* b3   = (const float*)d_in[16];
    float* outp = (float*)d_out;

    float* ws = (float*)d_ws;
    // --- zeroed region: BN stats + CSR counters ---
    float* gsum1 = ws + 0;           // 512
    float* gsq1  = ws + 512;
    float* gsum2 = ws + 1024;
    float* gsq2  = ws + 1536;
    float* gsum3 = ws + 2048;        // 128
    float* gsq3  = ws + 2176;        // 128
    int* cnt_cell = (int*)(ws + 2304);     // 50176
    int* cnt_tok  = cnt_cell + kBHW;       // 12544
    const size_t zero_bytes = (2304ull + kBHW + kROWS) * 4;
    // --- non-zeroed ---
    int* off_cell  = cnt_tok + kROWS;      // 50180 (padded)
    int* off_tok   = off_cell + 50180;     // 12548 (padded)
    int* fill_cell = off_tok + 12548;      // 50176
    int* fill_tok  = fill_cell + kBHW;     // 12544
    int* bsum      = fill_tok + kROWS;     // 256
    int* ihw       = bsum + 256;           // 50176
    int* tok_by_cell = ihw + kPTS;         // 50176
    int* cell_by_tok = tok_by_cell + kPTS; // 50176
    float* w_by_tok  = (float*)(cell_by_tok + kPTS); // 50176
    float* wT     = w_by_tok + kPTS;       // 4608 (transposed dw weights)
    float* scale1 = wT + 4608;
    float* shift1 = scale1 + 512;
    float* scale2 = shift1 + 512;
    float* shift2 = scale2 + 512;
    float* scale3 = shift2 + 512;
    float* shift3 = scale3 + 128;
    float* hbuf   = shift3 + 128;                       // 6,422,528 (h -> h2 -> h3)
    float* smap   = hbuf + (size_t)kROWS * kCHID;       // 25,690,112
    float* convo  = smap + (size_t)kBHW * kCHID;        // 25,690,112
    float* out3   = smap;                               // alias: smap dead after dwconv

    hipMemsetAsync(ws, 0, zero_bytes, stream);

    // fc1
    gemm_nt_bias<<<dim3(kROWS / 64, kCHID / 64), 256, 0, stream>>>(
        x, fc1w, fc1b, hbuf, kROWS, kCHID, kCIN);

    // CSR build + weight transpose
    grid_idx_k<<<kPTS / 256, 256, 0, stream>>>(loc, ihw);
    count_k<<<kPTS / 256, 256, 0, stream>>>(iagg, ihw, cnt_cell, cnt_tok);
    wtrans_k<<<18, 256, 0, stream>>>(dww, wT);
    scan1_k<<<kBHW / 256, 256, 0, stream>>>(cnt_cell, off_cell, bsum);
    scan2_k<<<1, 256, 0, stream>>>(bsum, kBHW / 256);
    scan3_k<<<kBHW / 256, 256, 0, stream>>>(off_cell, fill_cell, bsum, kBHW, kPTS);
    scan1_k<<<kROWS / 256, 256, 0, stream>>>(cnt_tok, off_tok, bsum);
    scan2_k<<<1, 256, 0, stream>>>(bsum, kROWS / 256);
    scan3_k<<<kROWS / 256, 256, 0, stream>>>(off_tok, fill_tok, bsum, kROWS, kPTS);
    fill_k<<<kPTS / 256, 256, 0, stream>>>(iagg, ihw, aw, fill_cell, fill_tok,
                                           tok_by_cell, cell_by_tok, w_by_tok);

    // BN1 + GELU
    colstats512_k<<<392, 512, 0, stream>>>(hbuf, gsum1, gsq1, 32);
    bn_coef_k<<<1, 512, 0, stream>>>(gsum1, gsq1, g1, b1, scale1, shift1, kCHID, 1.f / kROWS);
    bn_act_k<<<2048, 256, 0, stream>>>(hbuf, hbuf, scale1, shift1,
                                       (size_t)kROWS * kCHID / 4, kCHID / 4);

    // token -> map (zero-filled) -> dwconv -> token (+fused skip)
    gather_map_k<<<kBHW / 4, 256, 0, stream>>>(hbuf, off_cell, tok_by_cell, smap);
    dwconv_k<<<(kB * (kHW / 4)) / 2, 256, 0, stream>>>(smap, cnt_cell, wT, dwb, convo);
    gather_tok_k<<<kROWS / 4, 256, 0, stream>>>(convo, off_tok, cell_by_tok, w_by_tok,
                                                dwsw, hbuf);

    // BN2 + GELU
    colstats512_k<<<392, 512, 0, stream>>>(hbuf, gsum2, gsq2, 32);
    bn_coef_k<<<1, 512, 0, stream>>>(gsum2, gsq2, g2, b2, scale2, shift2, kCHID, 1.f / kROWS);
    bn_act_k<<<2048, 256, 0, stream>>>(hbuf, hbuf, scale2, shift2,
                                       (size_t)kROWS * kCHID / 4, kCHID / 4);

    // fc2
    gemm_nt_bias<<<dim3(kROWS / 64, kCOUT / 64), 256, 0, stream>>>(
        hbuf, fc2w, fc2b, out3, kROWS, kCOUT, kCHID);

    // BN3 + GELU -> out
    colstats128_k<<<392, 256, 0, stream>>>(out3, gsum3, gsq3, 32);
    bn_coef_k<<<1, 128, 0, stream>>>(gsum3, gsq3, g3, b3, scale3, shift3, kCOUT, 1.f / kROWS);
    bn_act_k<<<2048, 256, 0, stream>>>(out3, outp, scale3, shift3,
                                       (size_t)kROWS * kCOUT / 4, kCOUT / 4);
}

// Round 4
// 241.160 us; speedup vs baseline: 2.6439x; 1.2587x over previous
//
#include <hip/hip_runtime.h>
#include <math.h>

// Problem constants (fixed by the reference)
constexpr int kB    = 4;
constexpr int kN    = 3136;
constexpr int kN0   = 12544;
constexpr int kH    = 112, kW = 112;
constexpr int kHW   = kH * kW;          // 12544
constexpr int kCIN  = 128;
constexpr int kCHID = 512;
constexpr int kCOUT = 128;
constexpr int kROWS = kB * kN;          // 12544
constexpr int kPTS  = kB * kN0;         // 50176
constexpr int kBHW  = kB * kHW;         // 50176
constexpr float kEPS  = 1e-6f;
constexpr float kBEPS = 1e-5f;

typedef __attribute__((ext_vector_type(8))) short short8;
typedef __attribute__((ext_vector_type(4))) float f32x4;

__device__ __forceinline__ float gelu_f(float x) {
    return 0.5f * x * (1.0f + erff(x * 0.70710678118654752440f));
}
__device__ __forceinline__ float bf2f(short s) {
    union { unsigned u; float f; } v; v.u = ((unsigned)(unsigned short)s) << 16; return v.f;
}
__device__ __forceinline__ short f2bf(float f) {
    union { float f; unsigned u; } v; v.f = f;
    const unsigned r = v.u + 0x7fffu + ((v.u >> 16) & 1u);   // RNE
    return (short)(r >> 16);
}

// ---------------------------------------------------------------------------
// MFMA bf16 GEMM: C[M,N] = A[M,K](bf16) * W[N,K](bf16)^T + bias
// block=256 (4 waves); each wave: 16 rows x 64 cols; 16x16x32 MFMA.
// ---------------------------------------------------------------------------
__global__ __launch_bounds__(256) void gemm_bf16_k(
    const short* __restrict__ A, const short* __restrict__ W,
    const float* __restrict__ bias, float* __restrict__ C,
    int M, int N, int K)
{
    const int wave = threadIdx.x >> 6;
    const int lane = threadIdx.x & 63;
    const int r = lane & 15, kg = lane >> 4;
    const int bm = blockIdx.x * 64 + wave * 16;
    const int bn = blockIdx.y * 64;
    const short* arow = A + (size_t)(bm + r) * K + kg * 8;
    f32x4 acc[4];
#pragma unroll
    for (int j = 0; j < 4; ++j) {
        const float bz = bias[bn + j * 16 + r];
        acc[j][0] = bz; acc[j][1] = bz; acc[j][2] = bz; acc[j][3] = bz;
    }
    for (int k0 = 0; k0 < K; k0 += 32) {
        const short8 av = *(const short8*)(arow + k0);
#pragma unroll
        for (int j = 0; j < 4; ++j) {
            const short8 bv = *(const short8*)(W + (size_t)(bn + j * 16 + r) * K + k0 + kg * 8);
            acc[j] = __builtin_amdgcn_mfma_f32_16x16x32_bf16(av, bv, acc[j], 0, 0, 0);
        }
    }
#pragma unroll
    for (int j = 0; j < 4; ++j)
#pragma unroll
        for (int q = 0; q < 4; ++q)
            C[(size_t)(bm + kg * 4 + q) * N + bn + j * 16 + r] = acc[j][q];
}

// ---------------------------------------------------------------------------
// fp32 -> bf16 conversions for x, fc1_w, fc2_w (fused into one kernel)
// ---------------------------------------------------------------------------
__device__ __forceinline__ void cvt8(const float* __restrict__ in, short* __restrict__ out) {
    const float4 v0 = ((const float4*)in)[0];
    const float4 v1 = ((const float4*)in)[1];
    short8 o;
    o[0] = f2bf(v0.x); o[1] = f2bf(v0.y); o[2] = f2bf(v0.z); o[3] = f2bf(v0.w);
    o[4] = f2bf(v1.x); o[5] = f2bf(v1.y); o[6] = f2bf(v1.z); o[7] = f2bf(v1.w);
    *(short8*)out = o;
}

__global__ void cvt3_k(const float* __restrict__ a, short* __restrict__ ao, int na,
                       const float* __restrict__ b, short* __restrict__ bo, int nb,
                       const float* __restrict__ c, short* __restrict__ co, int nc)
{
    int t = (blockIdx.x * 256 + threadIdx.x) * 8;
    if (t < na) { cvt8(a + t, ao + t); return; }
    t -= na;
    if (t < nb) { cvt8(b + t, bo + t); return; }
    t -= nb;
    if (t < nc) { cvt8(c + t, co + t); }
}

// ---------------------------------------------------------------------------
// Grid index from loc_orig
// ---------------------------------------------------------------------------
__global__ void grid_idx_k(const float* __restrict__ loc, int* __restrict__ idx_hw)
{
    const int p = blockIdx.x * 256 + threadIdx.x;
    if (p >= kPTS) return;
    float lx = loc[(size_t)p * 2 + 0];
    float ly = loc[(size_t)p * 2 + 1];
    lx = fminf(fmaxf(lx, -1.f), 1.f) * 0.5f + 0.5f;
    ly = fminf(fmaxf(ly, -1.f), 1.f) * 0.5f + 0.5f;
    int gx = (int)rintf(lx * (float)(kW - 1)); gx = min(max(gx, 0), kW - 1);
    int gy = (int)rintf(ly * (float)(kH - 1)); gy = min(max(gy, 0), kH - 1);
    idx_hw[p] = gy * kW + gx;
}

// Depthwise weight transpose: [512][9] -> [9][512] bf16
__global__ void wtrans_k(const float* __restrict__ dww, short* __restrict__ wTb)
{
    const int i = blockIdx.x * 256 + threadIdx.x;
    if (i >= 9 * 512) return;
    const int tap = i / 512, c = i % 512;
    wTb[i] = f2bf(dww[c * 9 + tap]);
}

// ---------------------------------------------------------------------------
// CSR build: count -> exclusive scan -> fill
// ---------------------------------------------------------------------------
__global__ void count_k(const int* __restrict__ iagg, const int* __restrict__ ihw,
                        int* __restrict__ cnt_cell, int* __restrict__ cnt_tok)
{
    const int p = blockIdx.x * 256 + threadIdx.x;
    if (p >= kPTS) return;
    const int b = p / kN0;
    atomicAdd(cnt_cell + b * kHW + ihw[p], 1);
    atomicAdd(cnt_tok  + b * kN  + iagg[p], 1);
}

__global__ __launch_bounds__(256) void scan1_k(const int* __restrict__ cnt,
                                               int* __restrict__ off, int* __restrict__ bsum)
{
    __shared__ int sh[256];
    const int t = threadIdx.x;
    const int i = blockIdx.x * 256 + t;
    const int v = cnt[i];
    sh[t] = v; __syncthreads();
#pragma unroll
    for (int o = 1; o < 256; o <<= 1) {
        const int tmp = (t >= o) ? sh[t - o] : 0;
        __syncthreads();
        sh[t] += tmp;
        __syncthreads();
    }
    off[i] = sh[t] - v;
    if (t == 255) bsum[blockIdx.x] = sh[255];
}

__global__ __launch_bounds__(256) void scan2_k(int* __restrict__ bsum, int nb)
{
    __shared__ int sh[256];
    const int t = threadIdx.x;
    const int v = (t < nb) ? bsum[t] : 0;
    sh[t] = v; __syncthreads();
#pragma unroll
    for (int o = 1; o < 256; o <<= 1) {
        const int tmp = (t >= o) ? sh[t - o] : 0;
        __syncthreads();
        sh[t] += tmp;
        __syncthreads();
    }
    if (t < nb) bsum[t] = sh[t] - v;
}

__global__ __launch_bounds__(256) void scan3_k(int* __restrict__ off, int* __restrict__ fill,
                                               const int* __restrict__ bsum, int n, int total)
{
    const int i = blockIdx.x * 256 + threadIdx.x;
    const int v = off[i] + bsum[blockIdx.x];
    off[i] = v; fill[i] = v;
    if (i == 0) off[n] = total;
}

__global__ void fill_k(const int* __restrict__ iagg, const int* __restrict__ ihw,
                       const float* __restrict__ aw,
                       int* __restrict__ fill_cell, int* __restrict__ fill_tok,
                       int* __restrict__ tok_by_cell, int* __restrict__ cell_by_tok,
                       float* __restrict__ w_by_tok)
{
    const int p = blockIdx.x * 256 + threadIdx.x;
    if (p >= kPTS) return;
    const int b = p / kN0;
    const int tokrow = b * kN + iagg[p];
    const int cell   = b * kHW + ihw[p];
    const int cpos = atomicAdd(fill_cell + cell, 1);
    tok_by_cell[cpos] = tokrow;
    const int tpos = atomicAdd(fill_tok + tokrow, 1);
    cell_by_tok[tpos] = cell;
    w_by_tok[tpos] = aw[p];
}

// ---------------------------------------------------------------------------
// Column stats (per-channel sum/sumsq) over fp32 [rows, C]
// ---------------------------------------------------------------------------
__global__ __launch_bounds__(512) void colstats512_k(
    const float* __restrict__ X, float* __restrict__ gsum, float* __restrict__ gsq,
    int rows_per_blk)
{
    const int c = threadIdx.x;
    const int r0 = blockIdx.x * rows_per_blk;
    float s = 0.f, q = 0.f;
    for (int r = 0; r < rows_per_blk; ++r) {
        const float v = X[(size_t)(r0 + r) * kCHID + c];
        s += v; q += v * v;
    }
    atomicAdd(&gsum[c], s);
    atomicAdd(&gsq[c], q);
}

__global__ __launch_bounds__(256) void colstats128_k(
    const float* __restrict__ X, float* __restrict__ gsum, float* __restrict__ gsq,
    int rows_per_blk)
{
    const int c = threadIdx.x & 127;
    const int rr = threadIdx.x >> 7;
    const int r0 = blockIdx.x * rows_per_blk;
    float s = 0.f, q = 0.f;
    for (int r = rr; r < rows_per_blk; r += 2) {
        const float v = X[(size_t)(r0 + r) * kCOUT + c];
        s += v; q += v * v;
    }
    atomicAdd(&gsum[c], s);
    atomicAdd(&gsq[c], q);
}

__global__ void bn_coef_k(const float* __restrict__ gsum, const float* __restrict__ gsq,
                          const float* __restrict__ g, const float* __restrict__ bb,
                          float* __restrict__ scale, float* __restrict__ shift,
                          int C, float invn)
{
    const int c = blockIdx.x * blockDim.x + threadIdx.x;
    if (c >= C) return;
    const float m = gsum[c] * invn;
    const float v = fmaxf(gsq[c] * invn - m * m, 0.f);
    const float sc = g[c] * rsqrtf(v + kBEPS);
    scale[c] = sc;
    shift[c] = bb[c] - m * sc;
}

// BN+GELU, fp32 in -> bf16 out (512-channel layout)
__global__ __launch_bounds__(256) void bn_act_bf16_k(
    const float* __restrict__ in, short* __restrict__ out,
    const float* __restrict__ scale, const float* __restrict__ shift, size_t n8)
{
    const size_t stride = (size_t)gridDim.x * blockDim.x;
    for (size_t i = (size_t)blockIdx.x * blockDim.x + threadIdx.x; i < n8; i += stride) {
        const int c0 = (int)(i & 63) * 8;          // 512/8 groups per row
        const float4 v0 = ((const float4*)in)[i * 2];
        const float4 v1 = ((const float4*)in)[i * 2 + 1];
        const float4 sc0 = *(const float4*)(scale + c0);
        const float4 sc1 = *(const float4*)(scale + c0 + 4);
        const float4 sh0 = *(const float4*)(shift + c0);
        const float4 sh1 = *(const float4*)(shift + c0 + 4);
        short8 o;
        o[0] = f2bf(gelu_f(fmaf(v0.x, sc0.x, sh0.x)));
        o[1] = f2bf(gelu_f(fmaf(v0.y, sc0.y, sh0.y)));
        o[2] = f2bf(gelu_f(fmaf(v0.z, sc0.z, sh0.z)));
        o[3] = f2bf(gelu_f(fmaf(v0.w, sc0.w, sh0.w)));
        o[4] = f2bf(gelu_f(fmaf(v1.x, sc1.x, sh1.x)));
        o[5] = f2bf(gelu_f(fmaf(v1.y, sc1.y, sh1.y)));
        o[6] = f2bf(gelu_f(fmaf(v1.z, sc1.z, sh1.z)));
        o[7] = f2bf(gelu_f(fmaf(v1.w, sc1.w, sh1.w)));
        *(short8*)(out + i * 8) = o;
    }
}

// BN+GELU fp32->fp32 (final output, 128-channel layout)
__global__ __launch_bounds__(256) void bn_act_k(
    const float* __restrict__ in, float* __restrict__ out,
    const float* __restrict__ scale, const float* __restrict__ shift,
    size_t n4, int c4div)
{
    const size_t stride = (size_t)gridDim.x * blockDim.x;
    for (size_t i = (size_t)blockIdx.x * blockDim.x + threadIdx.x; i < n4; i += stride) {
        const int c0 = (int)(i % (size_t)c4div) * 4;
        float4 v = ((const float4*)in)[i];
        const float4 sc = *(const float4*)(scale + c0);
        const float4 sh = *(const float4*)(shift + c0);
        v.x = gelu_f(fmaf(v.x, sc.x, sh.x));
        v.y = gelu_f(fmaf(v.y, sc.y, sh.y));
        v.z = gelu_f(fmaf(v.z, sc.z, sh.z));
        v.w = gelu_f(fmaf(v.w, sc.w, sh.w));
        ((float4*)out)[i] = v;
    }
}

// ---------------------------------------------------------------------------
// token2map gather (bf16 in/out): one wave per cell, 8 ch/lane. Empty -> 0.
// ---------------------------------------------------------------------------
__global__ __launch_bounds__(256) void gather_map_b(
    const short* __restrict__ hb, const int* __restrict__ off,
    const int* __restrict__ toklist, short* __restrict__ smap)
{
    const int lane = threadIdx.x & 63;
    const int cell = blockIdx.x * 4 + (threadIdx.x >> 6);
    const int s = off[cell], e = off[cell + 1];
    float a[8] = {};
    for (int j = s; j < e; ++j) {
        const short8 v = *(const short8*)(hb + (size_t)toklist[j] * kCHID + lane * 8);
#pragma unroll
        for (int t = 0; t < 8; ++t) a[t] += bf2f(v[t]);
    }
    const float sc = 1.f / ((float)(e - s) + kEPS);
    short8 o;
#pragma unroll
    for (int t = 0; t < 8; ++t) o[t] = f2bf(a[t] * sc);
    *(short8*)(smap + (size_t)cell * kCHID + lane * 8) = o;
}

// ---------------------------------------------------------------------------
// Depthwise 3x3 bf16, zero-filled map. 2x2 cells x 8 ch per thread.
// ---------------------------------------------------------------------------
__global__ __launch_bounds__(256) void dwconv_b(
    const short* __restrict__ smap, const int* __restrict__ cnt,
    const short* __restrict__ wTb, const float* __restrict__ bdw,
    short* __restrict__ convo)
{
    constexpr int kTX = kW / 2;                 // 56
    const int c8 = threadIdx.x & 63;
    const int w  = blockIdx.x * 4 + (threadIdx.x >> 6);
    const int b   = w / (kTX * kTX);
    const int rem = w % (kTX * kTX);
    const int ty = rem / kTX, tx = rem % kTX;
    const int y0 = ty * 2, x0 = tx * 2;
    const int gbase = b * kHW;
    const int c0 = c8 * 8;

    const int cell00 = gbase + y0 * kW + x0;
    const int n00 = cnt[cell00],       n01 = cnt[cell00 + 1];
    const int n10 = cnt[cell00 + kW],  n11 = cnt[cell00 + kW + 1];
    if ((n00 | n01 | n10 | n11) == 0) return;

    float wf[9][8];
#pragma unroll
    for (int t = 0; t < 9; ++t) {
        const short8 wv = *(const short8*)(wTb + t * kCHID + c0);
#pragma unroll
        for (int j = 0; j < 8; ++j) wf[t][j] = bf2f(wv[j]);
    }
    float bz[8];
    {
        const float4 b0 = *(const float4*)(bdw + c0);
        const float4 b1 = *(const float4*)(bdw + c0 + 4);
        bz[0] = b0.x; bz[1] = b0.y; bz[2] = b0.z; bz[3] = b0.w;
        bz[4] = b1.x; bz[5] = b1.y; bz[6] = b1.z; bz[7] = b1.w;
    }
    float acc[2][2][8];
#pragma unroll
    for (int cy = 0; cy < 2; ++cy)
#pragma unroll
        for (int cx = 0; cx < 2; ++cx)
#pragma unroll
            for (int j = 0; j < 8; ++j) acc[cy][cx][j] = bz[j];

#pragma unroll
    for (int dy = 0; dy < 4; ++dy) {
        const int yy = y0 - 1 + dy;
        if ((unsigned)yy >= (unsigned)kH) continue;
#pragma unroll
        for (int dx = 0; dx < 4; ++dx) {
            const int xx = x0 - 1 + dx;
            if ((unsigned)xx >= (unsigned)kW) continue;
            const short8 tv = *(const short8*)(smap + (size_t)(gbase + yy * kW + xx) * kCHID + c0);
            float tf[8];
#pragma unroll
            for (int j = 0; j < 8; ++j) tf[j] = bf2f(tv[j]);
#pragma unroll
            for (int cy = 0; cy < 2; ++cy) {
                const int wy = dy - cy;
                if ((unsigned)wy >= 3u) continue;
#pragma unroll
                for (int cx = 0; cx < 2; ++cx) {
                    const int wx = dx - cx;
                    if ((unsigned)wx >= 3u) continue;
                    const float* wq = wf[wy * 3 + wx];
#pragma unroll
                    for (int j = 0; j < 8; ++j)
                        acc[cy][cx][j] = fmaf(wq[j], tf[j], acc[cy][cx][j]);
                }
            }
        }
    }
#pragma unroll
    for (int cy = 0; cy < 2; ++cy)
#pragma unroll
        for (int cx = 0; cx < 2; ++cx) {
            const int n = (cy == 0) ? (cx == 0 ? n00 : n01) : (cx == 0 ? n10 : n11);
            if (!n) continue;
            short8 o;
#pragma unroll
            for (int j = 0; j < 8; ++j) o[j] = f2bf(acc[cy][cx][j]);
            *(short8*)(convo + (size_t)(cell00 + cy * kW + cx) * kCHID + c0) = o;
        }
}

// ---------------------------------------------------------------------------
// map2token gather + fused skip: h2 = h*dws + num/(den+eps)  (fp32 out)
// ---------------------------------------------------------------------------
__global__ __launch_bounds__(256) void gather_tok_b(
    const short* __restrict__ convo, const int* __restrict__ off,
    const int* __restrict__ celllist, const float* __restrict__ wlist,
    const short* __restrict__ hb, const float* __restrict__ dws,
    float* __restrict__ h2)
{
    const int lane = threadIdx.x & 63;
    const int t = blockIdx.x * 4 + (threadIdx.x >> 6);
    const int s = off[t], e = off[t + 1];
    float a[8] = {};
    float den = 0.f;
    for (int j = s; j < e; ++j) {
        const float w = wlist[j];
        den += w;
        const short8 v = *(const short8*)(convo + (size_t)celllist[j] * kCHID + lane * 8);
#pragma unroll
        for (int k = 0; k < 8; ++k) a[k] = fmaf(w, bf2f(v[k]), a[k]);
    }
    const float r = 1.f / (den + kEPS);
    const short8 hv = *(const short8*)(hb + (size_t)t * kCHID + lane * 8);
    const float4 d0 = *(const float4*)(dws + lane * 8);
    const float4 d1 = *(const float4*)(dws + lane * 8 + 4);
    const float dd[8] = {d0.x, d0.y, d0.z, d0.w, d1.x, d1.y, d1.z, d1.w};
    float* orow = h2 + (size_t)t * kCHID + lane * 8;
    float4 o0, o1;
    o0.x = fmaf(bf2f(hv[0]), dd[0], a[0] * r);
    o0.y = fmaf(bf2f(hv[1]), dd[1], a[1] * r);
    o0.z = fmaf(bf2f(hv[2]), dd[2], a[2] * r);
    o0.w = fmaf(bf2f(hv[3]), dd[3], a[3] * r);
    o1.x = fmaf(bf2f(hv[4]), dd[4], a[4] * r);
    o1.y = fmaf(bf2f(hv[5]), dd[5], a[5] * r);
    o1.z = fmaf(bf2f(hv[6]), dd[6], a[6] * r);
    o1.w = fmaf(bf2f(hv[7]), dd[7], a[7] * r);
    ((float4*)orow)[0] = o0;
    ((float4*)orow)[1] = o1;
}

// ---------------------------------------------------------------------------
extern "C" void kernel_launch(void* const* d_in, const int* in_sizes, int n_in,
                              void* d_out, int out_size, void* d_ws, size_t ws_size,
                              hipStream_t stream)
{
    (void)in_sizes; (void)n_in; (void)out_size; (void)ws_size;
    const float* x    = (const float*)d_in[0];
    const float* loc  = (const float*)d_in[1];
    const int*   iagg = (const int*)  d_in[2];
    const float* aw   = (const float*)d_in[3];
    const float* fc1w = (const float*)d_in[4];
    const float* fc1b = (const float*)d_in[5];
    const float* g1   = (const float*)d_in[6];
    const float* b1   = (const float*)d_in[7];
    const float* dww  = (const float*)d_in[8];
    const float* dwb  = (const float*)d_in[9];
    const float* dwsw = (const float*)d_in[10];
    const float* g2   = (const float*)d_in[11];
    const float* b2   = (const float*)d_in[12];
    const float* fc2w = (const float*)d_in[13];
    const float* fc2b = (const float*)d_in[14];
    const float* g3   = (const float*)d_in[15];
    const float* b3   = (const float*)d_in[16];
    float* outp = (float*)d_out;

    float* ws = (float*)d_ws;
    // --- zeroed region: BN stats + CSR counters ---
    float* gsum1 = ws + 0;
    float* gsq1  = ws + 512;
    float* gsum2 = ws + 1024;
    float* gsq2  = ws + 1536;
    float* gsum3 = ws + 2048;
    float* gsq3  = ws + 2176;
    int* cnt_cell = (int*)(ws + 2304);     // 50176
    int* cnt_tok  = cnt_cell + kBHW;       // 12544
    const size_t zero_bytes = (2304ull + kBHW + kROWS) * 4;
    // --- non-zeroed ---
    int* off_cell  = cnt_tok + kROWS;      // 50180
    int* off_tok   = off_cell + 50180;     // 12548
    int* fill_cell = off_tok + 12548;      // 50176
    int* fill_tok  = fill_cell + kBHW;     // 12544
    int* bsum      = fill_tok + kROWS;     // 256
    int* ihw       = bsum + 256;           // 50176
    int* tok_by_cell = ihw + kPTS;         // 50176
    int* cell_by_tok = tok_by_cell + kPTS; // 50176
    float* w_by_tok  = (float*)(cell_by_tok + kPTS); // 50176
    short* wTb = (short*)(w_by_tok + kPTS);          // 4608 shorts = 2304 words
    short* xb  = wTb + 4608;                         // 1,605,632 shorts
    short* w1b = xb + (size_t)kROWS * kCIN;          // 65,536 shorts
    short* w2b = w1b + 512 * 128;                    // 65,536 shorts
    float* scale1 = (float*)(w2b + 128 * 512);
    float* shift1 = scale1 + 512;
    float* scale2 = shift1 + 512;
    float* shift2 = scale2 + 512;
    float* scale3 = shift2 + 512;
    float* shift3 = scale3 + 128;
    float* hbuf  = shift3 + 128;                     // fp32 [kROWS][512]
    short* hb16  = (short*)(hbuf + (size_t)kROWS * kCHID);   // bf16 [kROWS][512]
    short* smap  = hb16 + (size_t)kROWS * kCHID;             // bf16 [kBHW][512]
    short* convo = smap + (size_t)kBHW * kCHID;              // bf16 [kBHW][512]
    float* out3  = (float*)smap;     // alias: smap dead after dwconv (fp32 [kROWS][128])

    hipMemsetAsync(ws, 0, zero_bytes, stream);

    // bf16 conversions: x, fc1_w, fc2_w
    {
        const int na = kROWS * kCIN, nb = 512 * 128, nc = 128 * 512;
        const int tot8 = (na + nb + nc) / 8;
        cvt3_k<<<(tot8 + 255) / 256, 256, 0, stream>>>(x, xb, na, fc1w, w1b, nb, fc2w, w2b, nc);
    }

    // fc1 (MFMA bf16): hbuf = xb @ w1b^T + fc1b
    gemm_bf16_k<<<dim3(kROWS / 64, kCHID / 64), 256, 0, stream>>>(
        xb, w1b, fc1b, hbuf, kROWS, kCHID, kCIN);

    // CSR build + dw weight transpose
    grid_idx_k<<<kPTS / 256, 256, 0, stream>>>(loc, ihw);
    count_k<<<kPTS / 256, 256, 0, stream>>>(iagg, ihw, cnt_cell, cnt_tok);
    wtrans_k<<<18, 256, 0, stream>>>(dww, wTb);
    scan1_k<<<kBHW / 256, 256, 0, stream>>>(cnt_cell, off_cell, bsum);
    scan2_k<<<1, 256, 0, stream>>>(bsum, kBHW / 256);
    scan3_k<<<kBHW / 256, 256, 0, stream>>>(off_cell, fill_cell, bsum, kBHW, kPTS);
    scan1_k<<<kROWS / 256, 256, 0, stream>>>(cnt_tok, off_tok, bsum);
    scan2_k<<<1, 256, 0, stream>>>(bsum, kROWS / 256);
    scan3_k<<<kROWS / 256, 256, 0, stream>>>(off_tok, fill_tok, bsum, kROWS, kPTS);
    fill_k<<<kPTS / 256, 256, 0, stream>>>(iagg, ihw, aw, fill_cell, fill_tok,
                                           tok_by_cell, cell_by_tok, w_by_tok);

    // BN1 + GELU -> bf16
    colstats512_k<<<392, 512, 0, stream>>>(hbuf, gsum1, gsq1, 32);
    bn_coef_k<<<1, 512, 0, stream>>>(gsum1, gsq1, g1, b1, scale1, shift1, kCHID, 1.f / kROWS);
    bn_act_bf16_k<<<2048, 256, 0, stream>>>(hbuf, hb16, scale1, shift1,
                                            (size_t)kROWS * kCHID / 8);

    // token -> map (bf16, zero-filled) -> dwconv -> token (+fused skip, fp32)
    gather_map_b<<<kBHW / 4, 256, 0, stream>>>(hb16, off_cell, tok_by_cell, smap);
    dwconv_b<<<(kB * kHW / 4) / 4, 256, 0, stream>>>(smap, cnt_cell, wTb, dwb, convo);
    gather_tok_b<<<kROWS / 4, 256, 0, stream>>>(convo, off_tok, cell_by_tok, w_by_tok,
                                                hb16, dwsw, hbuf);

    // BN2 + GELU -> bf16 (reuse hb16; h dead after gather_tok)
    colstats512_k<<<392, 512, 0, stream>>>(hbuf, gsum2, gsq2, 32);
    bn_coef_k<<<1, 512, 0, stream>>>(gsum2, gsq2, g2, b2, scale2, shift2, kCHID, 1.f / kROWS);
    bn_act_bf16_k<<<2048, 256, 0, stream>>>(hbuf, hb16, scale2, shift2,
                                            (size_t)kROWS * kCHID / 8);

    // fc2 (MFMA bf16): out3 = hb16 @ w2b^T + fc2b
    gemm_bf16_k<<<dim3(kROWS / 64, kCOUT / 64), 256, 0, stream>>>(
        hb16, w2b, fc2b, out3, kROWS, kCOUT, kCHID);

    // BN3 + GELU -> out (fp32)
    colstats128_k<<<392, 256, 0, stream>>>(out3, gsum3, gsq3, 32);
    bn_coef_k<<<1, 128, 0, stream>>>(gsum3, gsq3, g3, b3, scale3, shift3, kCOUT, 1.f / kROWS);
    bn_act_k<<<2048, 256, 0, stream>>>(out3, outp, scale3, shift3,
                                       (size_t)kROWS * kCOUT / 4, kCOUT / 4);
}

// Round 5
// 221.109 us; speedup vs baseline: 2.8837x; 1.0907x over previous
//
#include <hip/hip_runtime.h>
#include <math.h>

// Problem constants (fixed by the reference)
constexpr int kB    = 4;
constexpr int kN    = 3136;
constexpr int kN0   = 12544;
constexpr int kH    = 112, kW = 112;
constexpr int kHW   = kH * kW;          // 12544
constexpr int kCIN  = 128;
constexpr int kCHID = 512;
constexpr int kCOUT = 128;
constexpr int kROWS = kB * kN;          // 12544
constexpr int kPTS  = kB * kN0;         // 50176
constexpr int kBHW  = kB * kHW;         // 50176
constexpr int kSEG  = kBHW + kROWS;     // 62720 combined CSR segments
constexpr float kEPS  = 1e-6f;
constexpr float kBEPS = 1e-5f;

typedef __attribute__((ext_vector_type(8))) short short8;
typedef __attribute__((ext_vector_type(4))) float f32x4;

__device__ __forceinline__ float gelu_f(float x) {
    return 0.5f * x * (1.0f + erff(x * 0.70710678118654752440f));
}
__device__ __forceinline__ float bf2f(short s) {
    union { unsigned u; float f; } v; v.u = ((unsigned)(unsigned short)s) << 16; return v.f;
}
__device__ __forceinline__ short f2bf(float f) {
    union { float f; unsigned u; } v; v.f = f;
    const unsigned r = v.u + 0x7fffu + ((v.u >> 16) & 1u);   // RNE
    return (short)(r >> 16);
}

// ---------------------------------------------------------------------------
// MFMA bf16 GEMM: C[M,N] = A[M,K](bf16) * W[N,K](bf16)^T + bias
// block=256 (4 waves); each wave: 16 rows x 64 cols; 16x16x32 MFMA.
// OUT16: store bf16, else fp32.
// ---------------------------------------------------------------------------
template <int OUT16>
__global__ __launch_bounds__(256) void gemm_bf16_k(
    const short* __restrict__ A, const short* __restrict__ W,
    const float* __restrict__ bias, void* __restrict__ Cv,
    int M, int N, int K)
{
    const int wave = threadIdx.x >> 6;
    const int lane = threadIdx.x & 63;
    const int r = lane & 15, kg = lane >> 4;
    const int bm = blockIdx.x * 64 + wave * 16;
    const int bn = blockIdx.y * 64;
    const short* arow = A + (size_t)(bm + r) * K + kg * 8;
    f32x4 acc[4];
#pragma unroll
    for (int j = 0; j < 4; ++j) {
        const float bz = bias[bn + j * 16 + r];
        acc[j][0] = bz; acc[j][1] = bz; acc[j][2] = bz; acc[j][3] = bz;
    }
    for (int k0 = 0; k0 < K; k0 += 32) {
        const short8 av = *(const short8*)(arow + k0);
#pragma unroll
        for (int j = 0; j < 4; ++j) {
            const short8 bv = *(const short8*)(W + (size_t)(bn + j * 16 + r) * K + k0 + kg * 8);
            acc[j] = __builtin_amdgcn_mfma_f32_16x16x32_bf16(av, bv, acc[j], 0, 0, 0);
        }
    }
#pragma unroll
    for (int j = 0; j < 4; ++j)
#pragma unroll
        for (int q = 0; q < 4; ++q) {
            const size_t idx = (size_t)(bm + kg * 4 + q) * N + bn + j * 16 + r;
            if constexpr (OUT16) ((short*)Cv)[idx] = f2bf(acc[j][q]);
            else                 ((float*)Cv)[idx] = acc[j][q];
        }
}
template __global__ void gemm_bf16_k<0>(const short*, const short*, const float*, void*, int, int, int);
template __global__ void gemm_bf16_k<1>(const short*, const short*, const float*, void*, int, int, int);

// ---------------------------------------------------------------------------
// fp32->bf16 conversions for x, fc1_w, fc2_w + dw-weight transpose [512][9]->[9][512]
// ---------------------------------------------------------------------------
__device__ __forceinline__ void cvt8(const float* __restrict__ in, short* __restrict__ out) {
    const float4 v0 = ((const float4*)in)[0];
    const float4 v1 = ((const float4*)in)[1];
    short8 o;
    o[0] = f2bf(v0.x); o[1] = f2bf(v0.y); o[2] = f2bf(v0.z); o[3] = f2bf(v0.w);
    o[4] = f2bf(v1.x); o[5] = f2bf(v1.y); o[6] = f2bf(v1.z); o[7] = f2bf(v1.w);
    *(short8*)out = o;
}

constexpr int kCVT8 = (kROWS * kCIN + 512 * 128 + 128 * 512) / 8;   // 217088

__global__ void cvt4_k(const float* __restrict__ a, short* __restrict__ ao, int na,
                       const float* __restrict__ b, short* __restrict__ bo, int nb,
                       const float* __restrict__ c, short* __restrict__ co,
                       const float* __restrict__ dww, short* __restrict__ wTb)
{
    const int i = blockIdx.x * 256 + threadIdx.x;
    if (i < kCVT8) {
        int t = i * 8;
        if (t < na) { cvt8(a + t, ao + t); return; }
        t -= na;
        if (t < nb) { cvt8(b + t, bo + t); return; }
        t -= nb;
        cvt8(c + t, co + t);
        return;
    }
    const int j = i - kCVT8;
    if (j < 9 * 512) {
        const int tap = j / 512, ch = j % 512;
        wTb[j] = f2bf(dww[ch * 9 + tap]);
    }
}

// ---------------------------------------------------------------------------
// count (+fused grid index): combined counts [cells(50176) | tokens(12544)]
// ---------------------------------------------------------------------------
__global__ void count_k(const float* __restrict__ loc, const int* __restrict__ iagg,
                        int* __restrict__ ihw, int* __restrict__ cnt)
{
    const int p = blockIdx.x * 256 + threadIdx.x;
    if (p >= kPTS) return;
    float lx = loc[(size_t)p * 2 + 0];
    float ly = loc[(size_t)p * 2 + 1];
    lx = fminf(fmaxf(lx, -1.f), 1.f) * 0.5f + 0.5f;
    ly = fminf(fmaxf(ly, -1.f), 1.f) * 0.5f + 0.5f;
    int gx = (int)rintf(lx * (float)(kW - 1)); gx = min(max(gx, 0), kW - 1);
    int gy = (int)rintf(ly * (float)(kH - 1)); gy = min(max(gy, 0), kH - 1);
    const int idx = gy * kW + gx;
    ihw[p] = idx;
    const int b = p / kN0;
    atomicAdd(cnt + b * kHW + idx, 1);
    atomicAdd(cnt + kBHW + b * kN + iagg[p], 1);
}

// ---------------------------------------------------------------------------
// exclusive scan over kSEG elements (3 kernels)
// ---------------------------------------------------------------------------
__global__ __launch_bounds__(256) void scan1_k(const int* __restrict__ cnt,
                                               int* __restrict__ off, int* __restrict__ bsum)
{
    __shared__ int sh[256];
    const int t = threadIdx.x;
    const int i = blockIdx.x * 256 + t;
    const int v = (i < kSEG) ? cnt[i] : 0;
    sh[t] = v; __syncthreads();
#pragma unroll
    for (int o = 1; o < 256; o <<= 1) {
        const int tmp = (t >= o) ? sh[t - o] : 0;
        __syncthreads();
        sh[t] += tmp;
        __syncthreads();
    }
    if (i < kSEG) off[i] = sh[t] - v;
    if (t == 255) bsum[blockIdx.x] = sh[255];
}

__global__ __launch_bounds__(256) void scan2_k(int* __restrict__ bsum, int nb)
{
    __shared__ int sh[256];
    const int t = threadIdx.x;
    const int v = (t < nb) ? bsum[t] : 0;
    sh[t] = v; __syncthreads();
#pragma unroll
    for (int o = 1; o < 256; o <<= 1) {
        const int tmp = (t >= o) ? sh[t - o] : 0;
        __syncthreads();
        sh[t] += tmp;
        __syncthreads();
    }
    if (t < nb) bsum[t] = sh[t] - v;
}

__global__ __launch_bounds__(256) void scan3_k(int* __restrict__ off, int* __restrict__ fill,
                                               const int* __restrict__ bsum)
{
    const int i = blockIdx.x * 256 + threadIdx.x;
    if (i >= kSEG) return;
    const int v = off[i] + bsum[blockIdx.x];
    off[i] = v; fill[i] = v;
    if (i == 0) off[kSEG] = 2 * kPTS;
}

__global__ void fill_k(const int* __restrict__ iagg, const int* __restrict__ ihw,
                       const float* __restrict__ aw, int* __restrict__ fill,
                       int* __restrict__ slotA, float* __restrict__ w_all)
{
    const int p = blockIdx.x * 256 + threadIdx.x;
    if (p >= kPTS) return;
    const int b = p / kN0;
    const int tokrow = b * kN + iagg[p];
    const int cell   = b * kHW + ihw[p];
    const int cpos = atomicAdd(fill + cell, 1);
    slotA[cpos] = tokrow;
    const int tpos = atomicAdd(fill + kBHW + tokrow, 1);
    slotA[tpos] = cell;
    w_all[tpos] = aw[p];
}

// ---------------------------------------------------------------------------
// Column stats over bf16 [rows][512]: vectorized + LDS reduce -> atomics
// ---------------------------------------------------------------------------
__global__ __launch_bounds__(256) void colstats_b(
    const short* __restrict__ X, float* __restrict__ gsum, float* __restrict__ gsq,
    int rows_per_blk)
{
    __shared__ float shs[4][512];
    __shared__ float shq[4][512];
    const int g = threadIdx.x & 63;
    const int rr = threadIdx.x >> 6;
    const int r0 = blockIdx.x * rows_per_blk;
    float s[8] = {}, q[8] = {};
    for (int r = rr; r < rows_per_blk; r += 4) {
        const short8 v = *(const short8*)(X + (size_t)(r0 + r) * kCHID + g * 8);
#pragma unroll
        for (int j = 0; j < 8; ++j) { const float f = bf2f(v[j]); s[j] += f; q[j] += f * f; }
    }
#pragma unroll
    for (int j = 0; j < 8; ++j) { shs[rr][g * 8 + j] = s[j]; shq[rr][g * 8 + j] = q[j]; }
    __syncthreads();
    const int c = threadIdx.x * 2;
    const float s0 = shs[0][c] + shs[1][c] + shs[2][c] + shs[3][c];
    const float s1 = shs[0][c+1] + shs[1][c+1] + shs[2][c+1] + shs[3][c+1];
    const float q0 = shq[0][c] + shq[1][c] + shq[2][c] + shq[3][c];
    const float q1 = shq[0][c+1] + shq[1][c+1] + shq[2][c+1] + shq[3][c+1];
    atomicAdd(&gsum[c], s0);   atomicAdd(&gsum[c+1], s1);
    atomicAdd(&gsq[c],  q0);   atomicAdd(&gsq[c+1],  q1);
}

// Column stats over fp32 [rows][128]
__global__ __launch_bounds__(256) void colstats128_k(
    const float* __restrict__ X, float* __restrict__ gsum, float* __restrict__ gsq,
    int rows_per_blk)
{
    const int c = threadIdx.x & 127;
    const int rr = threadIdx.x >> 7;
    const int r0 = blockIdx.x * rows_per_blk;
    float s = 0.f, q = 0.f;
    for (int r = rr; r < rows_per_blk; r += 2) {
        const float v = X[(size_t)(r0 + r) * kCOUT + c];
        s += v; q += v * v;
    }
    atomicAdd(&gsum[c], s);
    atomicAdd(&gsq[c], q);
}

// ---------------------------------------------------------------------------
// BN (inline coef from gsum/gsq) + GELU, bf16 -> bf16, [rows][512] layout
// ---------------------------------------------------------------------------
__global__ __launch_bounds__(256) void bn_act_b(
    const short* __restrict__ in, short* __restrict__ out,
    const float* __restrict__ gsum, const float* __restrict__ gsq,
    const float* __restrict__ g, const float* __restrict__ bb, float invn)
{
    __shared__ float ssc[512], ssh[512];
    {
        const int c = threadIdx.x * 2;
#pragma unroll
        for (int u = 0; u < 2; ++u) {
            const float m = gsum[c + u] * invn;
            const float v = fmaxf(gsq[c + u] * invn - m * m, 0.f);
            const float sc = g[c + u] * rsqrtf(v + kBEPS);
            ssc[c + u] = sc;
            ssh[c + u] = bb[c + u] - m * sc;
        }
    }
    __syncthreads();
    const size_t i = (size_t)blockIdx.x * 256 + threadIdx.x;   // over rows*512/8
    const int c0 = (int)(i & 63) * 8;
    const short8 v = *(const short8*)(in + i * 8);
    short8 o;
#pragma unroll
    for (int j = 0; j < 8; ++j)
        o[j] = f2bf(gelu_f(fmaf(bf2f(v[j]), ssc[c0 + j], ssh[c0 + j])));
    *(short8*)(out + i * 8) = o;
}

// BN (inline coef) + GELU, fp32 -> fp32, [rows][128] layout (final output)
__global__ __launch_bounds__(256) void bn_act_f128(
    const float* __restrict__ in, float* __restrict__ out,
    const float* __restrict__ gsum, const float* __restrict__ gsq,
    const float* __restrict__ g, const float* __restrict__ bb, float invn)
{
    __shared__ float ssc[128], ssh[128];
    if (threadIdx.x < 128) {
        const int c = threadIdx.x;
        const float m = gsum[c] * invn;
        const float v = fmaxf(gsq[c] * invn - m * m, 0.f);
        const float sc = g[c] * rsqrtf(v + kBEPS);
        ssc[c] = sc;
        ssh[c] = bb[c] - m * sc;
    }
    __syncthreads();
    const size_t i = (size_t)blockIdx.x * 256 + threadIdx.x;   // over rows*128/4
    const int c0 = (int)(i & 31) * 4;
    float4 v = ((const float4*)in)[i];
    v.x = gelu_f(fmaf(v.x, ssc[c0 + 0], ssh[c0 + 0]));
    v.y = gelu_f(fmaf(v.y, ssc[c0 + 1], ssh[c0 + 1]));
    v.z = gelu_f(fmaf(v.z, ssc[c0 + 2], ssh[c0 + 2]));
    v.w = gelu_f(fmaf(v.w, ssc[c0 + 3], ssh[c0 + 3]));
    ((float4*)out)[i] = v;
}

// ---------------------------------------------------------------------------
// token2map gather (bf16): one wave per cell, 8 ch/lane. Empty -> 0.
// ---------------------------------------------------------------------------
__global__ __launch_bounds__(256) void gather_map_b(
    const short* __restrict__ hb, const int* __restrict__ off,
    const int* __restrict__ toklist, short* __restrict__ smap)
{
    const int lane = threadIdx.x & 63;
    const int cell = blockIdx.x * 4 + (threadIdx.x >> 6);
    const int s = off[cell], e = off[cell + 1];
    float a[8] = {};
    for (int j = s; j < e; ++j) {
        const short8 v = *(const short8*)(hb + (size_t)toklist[j] * kCHID + lane * 8);
#pragma unroll
        for (int t = 0; t < 8; ++t) a[t] += bf2f(v[t]);
    }
    const float sc = 1.f / ((float)(e - s) + kEPS);
    short8 o;
#pragma unroll
    for (int t = 0; t < 8; ++t) o[t] = f2bf(a[t] * sc);
    *(short8*)(smap + (size_t)cell * kCHID + lane * 8) = o;
}

// ---------------------------------------------------------------------------
// Depthwise 3x3 bf16, zero-filled map. 2x2 cells x 8 ch per thread.
// ---------------------------------------------------------------------------
__global__ __launch_bounds__(256) void dwconv_b(
    const short* __restrict__ smap, const int* __restrict__ cnt,
    const short* __restrict__ wTb, const float* __restrict__ bdw,
    short* __restrict__ convo)
{
    constexpr int kTX = kW / 2;                 // 56
    const int c8 = threadIdx.x & 63;
    const int w  = blockIdx.x * 4 + (threadIdx.x >> 6);
    const int b   = w / (kTX * kTX);
    const int rem = w % (kTX * kTX);
    const int ty = rem / kTX, tx = rem % kTX;
    const int y0 = ty * 2, x0 = tx * 2;
    const int gbase = b * kHW;
    const int c0 = c8 * 8;

    const int cell00 = gbase + y0 * kW + x0;
    const int n00 = cnt[cell00],       n01 = cnt[cell00 + 1];
    const int n10 = cnt[cell00 + kW],  n11 = cnt[cell00 + kW + 1];
    if ((n00 | n01 | n10 | n11) == 0) return;

    float wf[9][8];
#pragma unroll
    for (int t = 0; t < 9; ++t) {
        const short8 wv = *(const short8*)(wTb + t * kCHID + c0);
#pragma unroll
        for (int j = 0; j < 8; ++j) wf[t][j] = bf2f(wv[j]);
    }
    float bz[8];
    {
        const float4 b0 = *(const float4*)(bdw + c0);
        const float4 b1 = *(const float4*)(bdw + c0 + 4);
        bz[0] = b0.x; bz[1] = b0.y; bz[2] = b0.z; bz[3] = b0.w;
        bz[4] = b1.x; bz[5] = b1.y; bz[6] = b1.z; bz[7] = b1.w;
    }
    float acc[2][2][8];
#pragma unroll
    for (int cy = 0; cy < 2; ++cy)
#pragma unroll
        for (int cx = 0; cx < 2; ++cx)
#pragma unroll
            for (int j = 0; j < 8; ++j) acc[cy][cx][j] = bz[j];

#pragma unroll
    for (int dy = 0; dy < 4; ++dy) {
        const int yy = y0 - 1 + dy;
        if ((unsigned)yy >= (unsigned)kH) continue;
#pragma unroll
        for (int dx = 0; dx < 4; ++dx) {
            const int xx = x0 - 1 + dx;
            if ((unsigned)xx >= (unsigned)kW) continue;
            const short8 tv = *(const short8*)(smap + (size_t)(gbase + yy * kW + xx) * kCHID + c0);
            float tf[8];
#pragma unroll
            for (int j = 0; j < 8; ++j) tf[j] = bf2f(tv[j]);
#pragma unroll
            for (int cy = 0; cy < 2; ++cy) {
                const int wy = dy - cy;
                if ((unsigned)wy >= 3u) continue;
#pragma unroll
                for (int cx = 0; cx < 2; ++cx) {
                    const int wx = dx - cx;
                    if ((unsigned)wx >= 3u) continue;
                    const float* wq = wf[wy * 3 + wx];
#pragma unroll
                    for (int j = 0; j < 8; ++j)
                        acc[cy][cx][j] = fmaf(wq[j], tf[j], acc[cy][cx][j]);
                }
            }
        }
    }
#pragma unroll
    for (int cy = 0; cy < 2; ++cy)
#pragma unroll
        for (int cx = 0; cx < 2; ++cx) {
            const int n = (cy == 0) ? (cx == 0 ? n00 : n01) : (cx == 0 ? n10 : n11);
            if (!n) continue;
            short8 o;
#pragma unroll
            for (int j = 0; j < 8; ++j) o[j] = f2bf(acc[cy][cx][j]);
            *(short8*)(convo + (size_t)(cell00 + cy * kW + cx) * kCHID + c0) = o;
        }
}

// ---------------------------------------------------------------------------
// map2token gather + fused skip: h2 = h*dws + num/(den+eps)  (bf16 out)
// ---------------------------------------------------------------------------
__global__ __launch_bounds__(256) void gather_tok_b(
    const short* __restrict__ convo, const int* __restrict__ off,
    const int* __restrict__ celllist, const float* __restrict__ wlist,
    const short* __restrict__ hb, const float* __restrict__ dws,
    short* __restrict__ h2)
{
    const int lane = threadIdx.x & 63;
    const int t = blockIdx.x * 4 + (threadIdx.x >> 6);
    const int s = off[t], e = off[t + 1];
    float a[8] = {};
    float den = 0.f;
    for (int j = s; j < e; ++j) {
        const float w = wlist[j];
        den += w;
        const short8 v = *(const short8*)(convo + (size_t)celllist[j] * kCHID + lane * 8);
#pragma unroll
        for (int k = 0; k < 8; ++k) a[k] = fmaf(w, bf2f(v[k]), a[k]);
    }
    const float r = 1.f / (den + kEPS);
    const short8 hv = *(const short8*)(hb + (size_t)t * kCHID + lane * 8);
    const float4 d0 = *(const float4*)(dws + lane * 8);
    const float4 d1 = *(const float4*)(dws + lane * 8 + 4);
    const float dd[8] = {d0.x, d0.y, d0.z, d0.w, d1.x, d1.y, d1.z, d1.w};
    short8 o;
#pragma unroll
    for (int k = 0; k < 8; ++k)
        o[k] = f2bf(fmaf(bf2f(hv[k]), dd[k], a[k] * r));
    *(short8*)(h2 + (size_t)t * kCHID + lane * 8) = o;
}

// ---------------------------------------------------------------------------
extern "C" void kernel_launch(void* const* d_in, const int* in_sizes, int n_in,
                              void* d_out, int out_size, void* d_ws, size_t ws_size,
                              hipStream_t stream)
{
    (void)in_sizes; (void)n_in; (void)out_size; (void)ws_size;
    const float* x    = (const float*)d_in[0];
    const float* loc  = (const float*)d_in[1];
    const int*   iagg = (const int*)  d_in[2];
    const float* aw   = (const float*)d_in[3];
    const float* fc1w = (const float*)d_in[4];
    const float* fc1b = (const float*)d_in[5];
    const float* g1   = (const float*)d_in[6];
    const float* b1   = (const float*)d_in[7];
    const float* dww  = (const float*)d_in[8];
    const float* dwb  = (const float*)d_in[9];
    const float* dwsw = (const float*)d_in[10];
    const float* g2   = (const float*)d_in[11];
    const float* b2   = (const float*)d_in[12];
    const float* fc2w = (const float*)d_in[13];
    const float* fc2b = (const float*)d_in[14];
    const float* g3   = (const float*)d_in[15];
    const float* b3   = (const float*)d_in[16];
    float* outp = (float*)d_out;

    float* ws = (float*)d_ws;
    // --- zeroed region: BN stats (2304 floats) + combined counts (62720 ints) ---
    float* gsum1 = ws + 0;
    float* gsq1  = ws + 512;
    float* gsum2 = ws + 1024;
    float* gsq2  = ws + 1536;
    float* gsum3 = ws + 2048;
    float* gsq3  = ws + 2176;
    int* cnt = (int*)(ws + 2304);                    // [kSEG]
    const size_t zero_bytes = (2304ull + kSEG) * 4;
    // --- non-zeroed (word offsets keep 16B alignment for short8 arrays) ---
    int*   off   = cnt + kSEG;                       // [kSEG+1] (+3 pad) -> 62724
    int*   fill  = off + 62724;                      // [kSEG]
    int*   bsum  = fill + kSEG;                      // [256]
    int*   ihw   = bsum + 256;                       // [kPTS]
    int*   slotA = ihw + kPTS;                       // [2*kPTS]
    float* w_all = (float*)(slotA + 2 * kPTS);       // [2*kPTS]
    short* wTb   = (short*)(w_all + 2 * kPTS);       // [4608]
    short* xb    = wTb + 4608;                       // [kROWS*kCIN]
    short* w1b   = xb + (size_t)kROWS * kCIN;        // [512*128]
    short* w2b   = w1b + 512 * 128;                  // [128*512]
    short* hraw  = w2b + 128 * 512;                  // bf16 [kROWS][512] (fc1 out; later h2 raw)
    short* hb16  = hraw + (size_t)kROWS * kCHID;     // bf16 [kROWS][512] (post BN+GELU)
    short* smap  = hb16 + (size_t)kROWS * kCHID;     // bf16 [kBHW][512]
    short* convo = smap + (size_t)kBHW * kCHID;      // bf16 [kBHW][512]
    float* out3  = (float*)smap;                     // alias: smap dead after dwconv

    hipMemsetAsync(ws, 0, zero_bytes, stream);

    // conversions (x, fc1_w, fc2_w -> bf16; dw weights -> [9][512] bf16)
    cvt4_k<<<(kCVT8 + 9 * 512 + 255) / 256, 256, 0, stream>>>(
        x, xb, kROWS * kCIN, fc1w, w1b, 512 * 128, fc2w, w2b, dww, wTb);

    // fc1 (MFMA bf16 -> bf16): hraw = xb @ w1b^T + fc1b
    gemm_bf16_k<1><<<dim3(kROWS / 64, kCHID / 64), 256, 0, stream>>>(
        xb, w1b, fc1b, hraw, kROWS, kCHID, kCIN);

    // CSR build (combined cell|token segments, one scan)
    count_k<<<kPTS / 256, 256, 0, stream>>>(loc, iagg, ihw, cnt);
    scan1_k<<<(kSEG + 255) / 256, 256, 0, stream>>>(cnt, off, bsum);
    scan2_k<<<1, 256, 0, stream>>>(bsum, (kSEG + 255) / 256);
    scan3_k<<<(kSEG + 255) / 256, 256, 0, stream>>>(off, fill, bsum);
    fill_k<<<kPTS / 256, 256, 0, stream>>>(iagg, ihw, aw, fill, slotA, w_all);

    // BN1 + GELU (stats on bf16; coef inline)
    colstats_b<<<196, 256, 0, stream>>>(hraw, gsum1, gsq1, 64);
    bn_act_b<<<(kROWS * kCHID / 8) / 256, 256, 0, stream>>>(
        hraw, hb16, gsum1, gsq1, g1, b1, 1.f / kROWS);

    // token -> map (zero-filled) -> dwconv -> token (+fused skip)
    gather_map_b<<<kBHW / 4, 256, 0, stream>>>(hb16, off, slotA, smap);
    dwconv_b<<<(kB * kHW / 4) / 4, 256, 0, stream>>>(smap, cnt, wTb, dwb, convo);
    gather_tok_b<<<kROWS / 4, 256, 0, stream>>>(convo, off + kBHW, slotA, w_all,
                                                hb16, dwsw, hraw);

    // BN2 + GELU
    colstats_b<<<196, 256, 0, stream>>>(hraw, gsum2, gsq2, 64);
    bn_act_b<<<(kROWS * kCHID / 8) / 256, 256, 0, stream>>>(
        hraw, hb16, gsum2, gsq2, g2, b2, 1.f / kROWS);

    // fc2 (MFMA bf16 -> fp32): out3 = hb16 @ w2b^T + fc2b
    gemm_bf16_k<0><<<dim3(kROWS / 64, kCOUT / 64), 256, 0, stream>>>(
        hb16, w2b, fc2b, out3, kROWS, kCOUT, kCHID);

    // BN3 + GELU -> out (fp32)
    colstats128_k<<<392, 256, 0, stream>>>(out3, gsum3, gsq3, 32);
    bn_act_f128<<<(kROWS * kCOUT / 4) / 256, 256, 0, stream>>>(
        out3, outp, gsum3, gsq3, g3, b3, 1.f / kROWS);
}